// Round 1
// baseline (615.874 us; speedup 1.0000x reference)
//
#include <hip/hip_runtime.h>
#include <cstdio>

// Problem constants
static constexpr int Bc = 64;     // batch
static constexpr int Nc = 4096;   // set size
static constexpr int Dc = 128;    // d_in
static constexpr int Mc = 1024;   // num ref points
static constexpr int Lc = 128;    // num projections

// ---------------------------------------------------------------------------
// Kernel 1: W = theta_v / ||row||, C[l] = sum_m ref[m,l]*weight[l,m]
// grid = L blocks, 128 threads
// ---------------------------------------------------------------------------
__global__ __launch_bounds__(128) void prep_kernel(
    const float* __restrict__ theta_v, const float* __restrict__ ref,
    const float* __restrict__ weight, float* __restrict__ W,
    float* __restrict__ C) {
  int l = blockIdx.x;
  int tid = threadIdx.x;  // 0..127 == d
  float w = theta_v[l * Dc + tid];
  float sq = w * w;
  // butterfly reduce within wave (64)
  #pragma unroll
  for (int off = 1; off < 64; off <<= 1) sq += __shfl_xor(sq, off, 64);
  __shared__ float s2[2];
  if ((tid & 63) == 0) s2[tid >> 6] = sq;
  __syncthreads();
  float norm = sqrtf(s2[0] + s2[1]);
  W[l * Dc + tid] = w / norm;

  float acc = 0.f;
  for (int m = tid; m < Mc; m += 128) acc += ref[(size_t)m * Lc + l] * weight[(size_t)l * Mc + m];
  #pragma unroll
  for (int off = 1; off < 64; off <<= 1) acc += __shfl_xor(acc, off, 64);
  __shared__ float c2[2];
  if ((tid & 63) == 0) c2[tid >> 6] = acc;
  __syncthreads();
  if (tid == 0) C[l] = c2[0] + c2[1];
}

// ---------------------------------------------------------------------------
// Kernel 2: build v[l][n].
//   stable argsort of ref[:,l] -> idx[rank] = original index
//   w2[l, idx[rank]] = weight[l, rank]
//   for each original index m': pos=(m'+1)(N+1)/(M+1)-1, i=floor, t=frac
//     v[l,i] += (1-t)*w2 ; v[l,i+1] += t*w2
// grid = L blocks, 256 threads
// ---------------------------------------------------------------------------
__global__ __launch_bounds__(256) void build_v_kernel(
    const float* __restrict__ ref, const float* __restrict__ weight,
    float* __restrict__ v) {
  int l = blockIdx.x;
  int tid = threadIdx.x;
  __shared__ float key[Mc];
  __shared__ int idx[Mc];
  __shared__ float vrow[Nc];  // 16 KB

  for (int m = tid; m < Mc; m += 256) {
    key[m] = ref[(size_t)m * Lc + l];
    idx[m] = m;
  }
  for (int i = tid; i < Nc; i += 256) vrow[i] = 0.f;
  __syncthreads();

  // stable bitonic sort ascending by (key, idx)
  for (int k = 2; k <= Mc; k <<= 1) {
    for (int j = k >> 1; j > 0; j >>= 1) {
      for (int t = tid; t < Mc / 2; t += 256) {
        int i = ((t & ~(j - 1)) << 1) | (t & (j - 1));
        int p = i | j;
        bool up = ((i & k) == 0);
        float a = key[i], b = key[p];
        int ia = idx[i], ib = idx[p];
        bool agt = (a > b) || (a == b && ia > ib);
        if (agt == up) {
          key[i] = b; key[p] = a;
          idx[i] = ib; idx[p] = ia;
        }
      }
      __syncthreads();
    }
  }

  for (int r = tid; r < Mc; r += 256) {
    float wv = weight[(size_t)l * Mc + r];  // weight[l, rank]
    int orig = idx[r];
    double pos = (double)(orig + 1) * (double)(Nc + 1) / (double)(Mc + 1) - 1.0;
    int i0 = (int)pos;  // pos in (2.99, 4092.01) -> safe
    float t = (float)(pos - (double)i0);
    atomicAdd(&vrow[i0], (1.0f - t) * wv);
    atomicAdd(&vrow[i0 + 1], t * wv);
  }
  __syncthreads();
  for (int i = tid; i < Nc; i += 256) v[(size_t)l * Nc + i] = vrow[i];
}

// ---------------------------------------------------------------------------
// Kernel 3: slices GEMM. sl[bloc][l][n] = sum_d X[bloc,n,d] * W[l,d]
// grid = (N/128, nb), 256 threads. Tile: 128 n x 128 l, d-chunks of 32.
// Thread micro-tile: 8n x 8l.  ty=tid&15 -> n, tx=tid>>4 -> l.
// ---------------------------------------------------------------------------
__global__ __launch_bounds__(256) void gemm_kernel(
    const float* __restrict__ X, const float* __restrict__ Wm,
    float* __restrict__ sl) {
  __shared__ float Xs[32][132];  // [d][n] transposed, padded (132*4=528, 16B aligned rows)
  __shared__ float Ws[32][132];  // [d][l]
  int bloc = blockIdx.y;
  int nbase = blockIdx.x * 128;
  const float* Xb = X + ((size_t)bloc * Nc + nbase) * Dc;
  int tid = threadIdx.x;
  int ty = tid & 15;   // n group
  int tx = tid >> 4;   // l group

  float acc[8][8] = {};

  for (int d0 = 0; d0 < Dc; d0 += 32) {
    #pragma unroll
    for (int r = 0; r < 4; ++r) {
      int id = tid + r * 256;
      int row = id >> 3;           // 0..127
      int c4 = (id & 7) * 4;       // 0..28
      float4 xv = *(const float4*)(Xb + (size_t)row * Dc + d0 + c4);
      Xs[c4 + 0][row] = xv.x; Xs[c4 + 1][row] = xv.y;
      Xs[c4 + 2][row] = xv.z; Xs[c4 + 3][row] = xv.w;
      float4 wv = *(const float4*)(Wm + (size_t)row * Dc + d0 + c4);  // row == l
      Ws[c4 + 0][row] = wv.x; Ws[c4 + 1][row] = wv.y;
      Ws[c4 + 2][row] = wv.z; Ws[c4 + 3][row] = wv.w;
    }
    __syncthreads();
    #pragma unroll
    for (int d = 0; d < 32; ++d) {
      float a[8], w[8];
      *(float4*)&a[0] = *(const float4*)&Xs[d][ty * 8];
      *(float4*)&a[4] = *(const float4*)&Xs[d][ty * 8 + 4];
      *(float4*)&w[0] = *(const float4*)&Ws[d][tx * 8];
      *(float4*)&w[4] = *(const float4*)&Ws[d][tx * 8 + 4];
      #pragma unroll
      for (int i = 0; i < 8; ++i)
        #pragma unroll
        for (int j = 0; j < 8; ++j)
          acc[i][j] += a[i] * w[j];
    }
    __syncthreads();
  }

  // write: for each l (tx*8+j), 8 contiguous n at nbase+ty*8
  #pragma unroll
  for (int j = 0; j < 8; ++j) {
    int l = tx * 8 + j;
    float* dst = sl + ((size_t)bloc * Lc + l) * Nc + nbase + ty * 8;
    float4 o0 = make_float4(acc[0][j], acc[1][j], acc[2][j], acc[3][j]);
    float4 o1 = make_float4(acc[4][j], acc[5][j], acc[6][j], acc[7][j]);
    *(float4*)dst = o0;
    *(float4*)(dst + 4) = o1;
  }
}

// ---------------------------------------------------------------------------
// Kernel 4: per (b,l): bitonic sort 4096 f32 in LDS, then dot with v[l,:].
// out[b,l] = C[l] - dot.  grid = nb*L blocks, 256 threads.
// ---------------------------------------------------------------------------
__global__ __launch_bounds__(256) void sort_dot_kernel(
    const float* __restrict__ sl, const float* __restrict__ v,
    const float* __restrict__ C, float* __restrict__ out, int b0) {
  __shared__ float s[Nc];  // 16 KB
  int l = blockIdx.x & (Lc - 1);
  int bloc = blockIdx.x >> 7;
  int tid = threadIdx.x;
  const float* src = sl + ((size_t)bloc * Lc + l) * Nc;

  for (int i = tid; i < Nc / 4; i += 256) {
    ((float4*)s)[i] = ((const float4*)src)[i];
  }
  __syncthreads();

  for (int k = 2; k <= Nc; k <<= 1) {
    for (int j = k >> 1; j > 0; j >>= 1) {
      #pragma unroll
      for (int u = 0; u < Nc / 2 / 256; ++u) {
        int t = tid + u * 256;
        int i = ((t & ~(j - 1)) << 1) | (t & (j - 1));
        int p = i | j;
        bool up = ((i & k) == 0);
        float a = s[i], b = s[p];
        if ((a > b) == up) { s[i] = b; s[p] = a; }
      }
      __syncthreads();
    }
  }

  const float* vr = v + (size_t)l * Nc;
  float acc = 0.f;
  for (int i = tid; i < Nc; i += 256) acc += s[i] * vr[i];
  #pragma unroll
  for (int off = 1; off < 64; off <<= 1) acc += __shfl_xor(acc, off, 64);
  __shared__ float red[4];
  if ((tid & 63) == 0) red[tid >> 6] = acc;
  __syncthreads();
  if (tid == 0) {
    int b = b0 + bloc;
    out[(size_t)b * Lc + l] = C[l] - (red[0] + red[1] + red[2] + red[3]);
  }
}

// ---------------------------------------------------------------------------
extern "C" void kernel_launch(void* const* d_in, const int* in_sizes, int n_in,
                              void* d_out, int out_size, void* d_ws, size_t ws_size,
                              hipStream_t stream) {
  const float* X       = (const float*)d_in[0];  // [B,N,D]
  const float* theta_v = (const float*)d_in[1];  // [L,D]
  const float* ref     = (const float*)d_in[2];  // [M,L]
  const float* weight  = (const float*)d_in[3];  // [L,M]
  float* out = (float*)d_out;                    // [B,L]

  // workspace layout: v [L*N] | W [L*D] | C [128] | sl [chunk*L*N]
  float* v  = (float*)d_ws;
  float* W  = v + (size_t)Lc * Nc;
  float* Cc = W + (size_t)Lc * Dc;
  float* sl = Cc + 128;
  size_t used = (size_t)((char*)sl - (char*)d_ws);
  size_t per_b = (size_t)Lc * Nc * sizeof(float);  // 2 MB per batch element
  int chunk = 1;
  if (ws_size > used + per_b) {
    size_t c = (ws_size - used) / per_b;
    chunk = (int)(c > (size_t)Bc ? (size_t)Bc : c);
    if (chunk < 1) chunk = 1;
  }
  fprintf(stderr, "[PSWE] ws_size=%zu used_fixed=%zu chunk=%d\n", ws_size, used, chunk);

  prep_kernel<<<Lc, 128, 0, stream>>>(theta_v, ref, weight, W, Cc);
  build_v_kernel<<<Lc, 256, 0, stream>>>(ref, weight, v);

  for (int b0 = 0; b0 < Bc; b0 += chunk) {
    int nb = (Bc - b0) < chunk ? (Bc - b0) : chunk;
    dim3 g1(Nc / 128, nb);
    gemm_kernel<<<g1, 256, 0, stream>>>(X + (size_t)b0 * Nc * Dc, W, sl);
    sort_dot_kernel<<<(size_t)nb * Lc, 256, 0, stream>>>(sl, v, Cc, out, b0);
  }
}

// Round 2
// 334.814 us; speedup vs baseline: 1.8395x; 1.8395x over previous
//
#include <hip/hip_runtime.h>

// Problem constants
static constexpr int Bc = 64;     // batch
static constexpr int Nc = 4096;   // set size
static constexpr int Dc = 128;    // d_in
static constexpr int Mc = 1024;   // num ref points
static constexpr int Lc = 128;    // num projections

// ---------------------------------------------------------------------------
// Kernel 1: W = theta_v / ||row||, C[l] = sum_m ref[m,l]*weight[l,m]
// ---------------------------------------------------------------------------
__global__ __launch_bounds__(128) void prep_kernel(
    const float* __restrict__ theta_v, const float* __restrict__ ref,
    const float* __restrict__ weight, float* __restrict__ W,
    float* __restrict__ C) {
  int l = blockIdx.x;
  int tid = threadIdx.x;  // 0..127 == d
  float w = theta_v[l * Dc + tid];
  float sq = w * w;
  #pragma unroll
  for (int off = 1; off < 64; off <<= 1) sq += __shfl_xor(sq, off, 64);
  __shared__ float s2[2];
  if ((tid & 63) == 0) s2[tid >> 6] = sq;
  __syncthreads();
  float norm = sqrtf(s2[0] + s2[1]);
  W[l * Dc + tid] = w / norm;

  float acc = 0.f;
  for (int m = tid; m < Mc; m += 128) acc += ref[(size_t)m * Lc + l] * weight[(size_t)l * Mc + m];
  #pragma unroll
  for (int off = 1; off < 64; off <<= 1) acc += __shfl_xor(acc, off, 64);
  __shared__ float c2[2];
  if ((tid & 63) == 0) c2[tid >> 6] = acc;
  __syncthreads();
  if (tid == 0) C[l] = c2[0] + c2[1];
}

// ---------------------------------------------------------------------------
// Kernel 2: build v[l][n] (stable argsort of ref column + interp stencil scatter)
// ---------------------------------------------------------------------------
__global__ __launch_bounds__(256) void build_v_kernel(
    const float* __restrict__ ref, const float* __restrict__ weight,
    float* __restrict__ v) {
  int l = blockIdx.x;
  int tid = threadIdx.x;
  __shared__ float key[Mc];
  __shared__ int idx[Mc];
  __shared__ float vrow[Nc];

  for (int m = tid; m < Mc; m += 256) {
    key[m] = ref[(size_t)m * Lc + l];
    idx[m] = m;
  }
  for (int i = tid; i < Nc; i += 256) vrow[i] = 0.f;
  __syncthreads();

  // stable bitonic sort ascending by (key, idx)
  for (int k = 2; k <= Mc; k <<= 1) {
    for (int j = k >> 1; j > 0; j >>= 1) {
      for (int t = tid; t < Mc / 2; t += 256) {
        int i = ((t & ~(j - 1)) << 1) | (t & (j - 1));
        int p = i | j;
        bool up = ((i & k) == 0);
        float a = key[i], b = key[p];
        int ia = idx[i], ib = idx[p];
        bool agt = (a > b) || (a == b && ia > ib);
        if (agt == up) {
          key[i] = b; key[p] = a;
          idx[i] = ib; idx[p] = ia;
        }
      }
      __syncthreads();
    }
  }

  for (int r = tid; r < Mc; r += 256) {
    float wv = weight[(size_t)l * Mc + r];  // weight[l, rank]
    int orig = idx[r];
    double pos = (double)(orig + 1) * (double)(Nc + 1) / (double)(Mc + 1) - 1.0;
    int i0 = (int)pos;
    float t = (float)(pos - (double)i0);
    atomicAdd(&vrow[i0], (1.0f - t) * wv);
    atomicAdd(&vrow[i0 + 1], t * wv);
  }
  __syncthreads();
  for (int i = tid; i < Nc; i += 256) v[(size_t)l * Nc + i] = vrow[i];
}

// ---------------------------------------------------------------------------
// Kernel 3: slices GEMM. sl[bloc][l][n] = sum_d X[bloc,n,d] * W[l,d]
// ---------------------------------------------------------------------------
__global__ __launch_bounds__(256) void gemm_kernel(
    const float* __restrict__ X, const float* __restrict__ Wm,
    float* __restrict__ sl) {
  __shared__ float Xs[32][132];
  __shared__ float Ws[32][132];
  int bloc = blockIdx.y;
  int nbase = blockIdx.x * 128;
  const float* Xb = X + ((size_t)bloc * Nc + nbase) * Dc;
  int tid = threadIdx.x;
  int ty = tid & 15;   // n group
  int tx = tid >> 4;   // l group

  float acc[8][8] = {};

  for (int d0 = 0; d0 < Dc; d0 += 32) {
    #pragma unroll
    for (int r = 0; r < 4; ++r) {
      int id = tid + r * 256;
      int row = id >> 3;
      int c4 = (id & 7) * 4;
      float4 xv = *(const float4*)(Xb + (size_t)row * Dc + d0 + c4);
      Xs[c4 + 0][row] = xv.x; Xs[c4 + 1][row] = xv.y;
      Xs[c4 + 2][row] = xv.z; Xs[c4 + 3][row] = xv.w;
      float4 wv = *(const float4*)(Wm + (size_t)row * Dc + d0 + c4);
      Ws[c4 + 0][row] = wv.x; Ws[c4 + 1][row] = wv.y;
      Ws[c4 + 2][row] = wv.z; Ws[c4 + 3][row] = wv.w;
    }
    __syncthreads();
    #pragma unroll
    for (int d = 0; d < 32; ++d) {
      float a[8], w[8];
      *(float4*)&a[0] = *(const float4*)&Xs[d][ty * 8];
      *(float4*)&a[4] = *(const float4*)&Xs[d][ty * 8 + 4];
      *(float4*)&w[0] = *(const float4*)&Ws[d][tx * 8];
      *(float4*)&w[4] = *(const float4*)&Ws[d][tx * 8 + 4];
      #pragma unroll
      for (int i = 0; i < 8; ++i)
        #pragma unroll
        for (int j = 0; j < 8; ++j)
          acc[i][j] += a[i] * w[j];
    }
    __syncthreads();
  }

  #pragma unroll
  for (int j = 0; j < 8; ++j) {
    int l = tx * 8 + j;
    float* dst = sl + ((size_t)bloc * Lc + l) * Nc + nbase + ty * 8;
    float4 o0 = make_float4(acc[0][j], acc[1][j], acc[2][j], acc[3][j]);
    float4 o1 = make_float4(acc[4][j], acc[5][j], acc[6][j], acc[7][j]);
    *(float4*)dst = o0;
    *(float4*)(dst + 4) = o1;
  }
}

// ---------------------------------------------------------------------------
// Kernel 4: radix-rank "sort" + dot.
// Per (b,l): bin 4096 values into 4096 value-uniform bins (values ~ N(0,1)),
// histogram -> prefix -> scatter -> exact rank within tiny bin segment
// (tie-break by scatter position; ties are equal values so output is
// order-independent) -> scatter to sorted array -> coalesced dot with v.
// grid = nb*L blocks, 256 threads.
// ---------------------------------------------------------------------------
__global__ __launch_bounds__(256) void rank_dot_kernel(
    const float* __restrict__ sl, const float* __restrict__ v,
    const float* __restrict__ C, float* __restrict__ out, int b0) {
  constexpr int NB = 4096;
  constexpr float LO = -6.0f;
  constexpr float SCALE = (float)NB / 12.0f;

  __shared__ int pref[NB + 4];   // histogram, then exclusive prefix (+sentinel)
  __shared__ int cnt[NB];        // scatter counters; later reused as ssorted
  __shared__ float skey[Nc];     // bin-ordered keys
  __shared__ int wsum[4];
  __shared__ float red[4];

  int l = blockIdx.x & (Lc - 1);
  int bloc = blockIdx.x >> 7;
  int tid = threadIdx.x;
  const float* src = sl + ((size_t)bloc * Lc + l) * Nc;

  // load this thread's 16 contiguous elements
  float x[16];
  {
    const float4* s4 = (const float4*)src;
    #pragma unroll
    for (int j = 0; j < 4; ++j) {
      float4 f = s4[tid * 4 + j];
      x[j * 4 + 0] = f.x; x[j * 4 + 1] = f.y;
      x[j * 4 + 2] = f.z; x[j * 4 + 3] = f.w;
    }
  }

  for (int i = tid; i < NB; i += 256) { pref[i] = 0; cnt[i] = 0; }
  if (tid == 0) pref[NB] = Nc;
  __syncthreads();

  // histogram
  int bb[16];
  #pragma unroll
  for (int j = 0; j < 16; ++j) {
    int bi = (int)((x[j] - LO) * SCALE);
    bi = bi < 0 ? 0 : (bi > NB - 1 ? NB - 1 : bi);
    bb[j] = bi;
    atomicAdd(&pref[bi], 1);
  }
  __syncthreads();

  // exclusive prefix sum over 4096 bins (16 serial per thread + block scan)
  {
    int base_ = tid * 16;
    int loc[16]; int s = 0;
    #pragma unroll
    for (int j = 0; j < 16; ++j) loc[j] = pref[base_ + j];
    #pragma unroll
    for (int j = 0; j < 16; ++j) { int c = loc[j]; loc[j] = s; s += c; }
    int lane = tid & 63, wv = tid >> 6;
    int inc = s;
    #pragma unroll
    for (int off = 1; off < 64; off <<= 1) {
      int o = __shfl_up(inc, off, 64);
      if (lane >= off) inc += o;
    }
    if (lane == 63) wsum[wv] = inc;
    __syncthreads();
    int wbase = 0;
    #pragma unroll
    for (int w = 0; w < 4; ++w) if (w < wv) wbase += wsum[w];
    int tbase = wbase + inc - s;  // exclusive across threads
    #pragma unroll
    for (int j = 0; j < 16; ++j) pref[base_ + j] = tbase + loc[j];
  }
  __syncthreads();

  // scatter into bin-ordered array
  int pp[16];
  #pragma unroll
  for (int j = 0; j < 16; ++j) {
    int ofs = atomicAdd(&cnt[bb[j]], 1);
    int p = pref[bb[j]] + ofs;
    pp[j] = p;
    skey[p] = x[j];
  }
  __syncthreads();

  // exact rank within bin segment, scatter to sorted position.
  // cnt is dead now; reuse its space as the sorted-value array.
  float* ssorted = (float*)cnt;
  #pragma unroll
  for (int j = 0; j < 16; ++j) {
    int lo_ = pref[bb[j]];
    int hi_ = pref[bb[j] + 1];
    float xx = x[j];
    int myp = pp[j];
    int r = lo_;
    for (int q = lo_; q < hi_; ++q) {
      float y = skey[q];
      r += (y < xx || (y == xx && q < myp)) ? 1 : 0;
    }
    ssorted[r] = xx;
  }
  __syncthreads();

  // coalesced dot with v row
  const float4* v4 = (const float4*)(v + (size_t)l * Nc);
  const float4* sv4 = (const float4*)ssorted;
  float acc = 0.f;
  for (int i = tid; i < Nc / 4; i += 256) {
    float4 a = sv4[i], w = v4[i];
    acc += a.x * w.x + a.y * w.y + a.z * w.z + a.w * w.w;
  }
  #pragma unroll
  for (int off = 1; off < 64; off <<= 1) acc += __shfl_xor(acc, off, 64);
  if ((tid & 63) == 0) red[tid >> 6] = acc;
  __syncthreads();
  if (tid == 0) {
    int b = b0 + bloc;
    out[(size_t)b * Lc + l] = C[l] - (red[0] + red[1] + red[2] + red[3]);
  }
}

// ---------------------------------------------------------------------------
extern "C" void kernel_launch(void* const* d_in, const int* in_sizes, int n_in,
                              void* d_out, int out_size, void* d_ws, size_t ws_size,
                              hipStream_t stream) {
  const float* X       = (const float*)d_in[0];  // [B,N,D]
  const float* theta_v = (const float*)d_in[1];  // [L,D]
  const float* ref     = (const float*)d_in[2];  // [M,L]
  const float* weight  = (const float*)d_in[3];  // [L,M]
  float* out = (float*)d_out;                    // [B,L]

  // workspace layout: v [L*N] | W [L*D] | C [128] | sl [chunk*L*N]
  float* v  = (float*)d_ws;
  float* W  = v + (size_t)Lc * Nc;
  float* Cc = W + (size_t)Lc * Dc;
  float* sl = Cc + 128;
  size_t used = (size_t)((char*)sl - (char*)d_ws);
  size_t per_b = (size_t)Lc * Nc * sizeof(float);  // 2 MB per batch element
  int chunk = 1;
  if (ws_size > used + per_b) {
    size_t c = (ws_size - used) / per_b;
    chunk = (int)(c > (size_t)Bc ? (size_t)Bc : c);
    if (chunk < 1) chunk = 1;
  }

  prep_kernel<<<Lc, 128, 0, stream>>>(theta_v, ref, weight, W, Cc);
  build_v_kernel<<<Lc, 256, 0, stream>>>(ref, weight, v);

  for (int b0 = 0; b0 < Bc; b0 += chunk) {
    int nb = (Bc - b0) < chunk ? (Bc - b0) : chunk;
    dim3 g1(Nc / 128, nb);
    gemm_kernel<<<g1, 256, 0, stream>>>(X + (size_t)b0 * Nc * Dc, W, sl);
    rank_dot_kernel<<<(size_t)nb * Lc, 256, 0, stream>>>(sl, v, Cc, out, b0);
  }
}

// Round 3
// 291.912 us; speedup vs baseline: 2.1098x; 1.1470x over previous
//
#include <hip/hip_runtime.h>

// Problem constants
static constexpr int Bc = 64;     // batch
static constexpr int Nc = 4096;   // set size
static constexpr int Dc = 128;    // d_in
static constexpr int Mc = 1024;   // num ref points
static constexpr int Lc = 128;    // num projections

// ---------------------------------------------------------------------------
// Kernel 1: W = theta_v / ||row||, C[l] = sum_m ref[m,l]*weight[l,m]
// ---------------------------------------------------------------------------
__global__ __launch_bounds__(128) void prep_kernel(
    const float* __restrict__ theta_v, const float* __restrict__ ref,
    const float* __restrict__ weight, float* __restrict__ W,
    float* __restrict__ C) {
  int l = blockIdx.x;
  int tid = threadIdx.x;  // 0..127 == d
  float w = theta_v[l * Dc + tid];
  float sq = w * w;
  #pragma unroll
  for (int off = 1; off < 64; off <<= 1) sq += __shfl_xor(sq, off, 64);
  __shared__ float s2[2];
  if ((tid & 63) == 0) s2[tid >> 6] = sq;
  __syncthreads();
  float norm = sqrtf(s2[0] + s2[1]);
  W[l * Dc + tid] = w / norm;

  float acc = 0.f;
  for (int m = tid; m < Mc; m += 128) acc += ref[(size_t)m * Lc + l] * weight[(size_t)l * Mc + m];
  #pragma unroll
  for (int off = 1; off < 64; off <<= 1) acc += __shfl_xor(acc, off, 64);
  __shared__ float c2[2];
  if ((tid & 63) == 0) c2[tid >> 6] = acc;
  __syncthreads();
  if (tid == 0) C[l] = c2[0] + c2[1];
}

// ---------------------------------------------------------------------------
// Kernel 2: build v[l][n] (stable argsort of ref column + interp stencil scatter)
// ---------------------------------------------------------------------------
__global__ __launch_bounds__(256) void build_v_kernel(
    const float* __restrict__ ref, const float* __restrict__ weight,
    float* __restrict__ v) {
  int l = blockIdx.x;
  int tid = threadIdx.x;
  __shared__ float key[Mc];
  __shared__ int idx[Mc];
  __shared__ float vrow[Nc];

  for (int m = tid; m < Mc; m += 256) {
    key[m] = ref[(size_t)m * Lc + l];
    idx[m] = m;
  }
  for (int i = tid; i < Nc; i += 256) vrow[i] = 0.f;
  __syncthreads();

  // stable bitonic sort ascending by (key, idx)
  for (int k = 2; k <= Mc; k <<= 1) {
    for (int j = k >> 1; j > 0; j >>= 1) {
      for (int t = tid; t < Mc / 2; t += 256) {
        int i = ((t & ~(j - 1)) << 1) | (t & (j - 1));
        int p = i | j;
        bool up = ((i & k) == 0);
        float a = key[i], b = key[p];
        int ia = idx[i], ib = idx[p];
        bool agt = (a > b) || (a == b && ia > ib);
        if (agt == up) {
          key[i] = b; key[p] = a;
          idx[i] = ib; idx[p] = ia;
        }
      }
      __syncthreads();
    }
  }

  for (int r = tid; r < Mc; r += 256) {
    float wv = weight[(size_t)l * Mc + r];  // weight[l, rank]
    int orig = idx[r];
    double pos = (double)(orig + 1) * (double)(Nc + 1) / (double)(Mc + 1) - 1.0;
    int i0 = (int)pos;
    float t = (float)(pos - (double)i0);
    atomicAdd(&vrow[i0], (1.0f - t) * wv);
    atomicAdd(&vrow[i0 + 1], t * wv);
  }
  __syncthreads();
  for (int i = tid; i < Nc; i += 256) v[(size_t)l * Nc + i] = vrow[i];
}

// ---------------------------------------------------------------------------
// Kernel 3: slices GEMM. sl[bloc][l][n] = sum_d X[bloc,n,d] * W[l,d]
// ---------------------------------------------------------------------------
__global__ __launch_bounds__(256) void gemm_kernel(
    const float* __restrict__ X, const float* __restrict__ Wm,
    float* __restrict__ sl) {
  __shared__ float Xs[32][132];
  __shared__ float Ws[32][132];
  int bloc = blockIdx.y;
  int nbase = blockIdx.x * 128;
  const float* Xb = X + ((size_t)bloc * Nc + nbase) * Dc;
  int tid = threadIdx.x;
  int ty = tid & 15;   // n group
  int tx = tid >> 4;   // l group

  float acc[8][8] = {};

  for (int d0 = 0; d0 < Dc; d0 += 32) {
    #pragma unroll
    for (int r = 0; r < 4; ++r) {
      int id = tid + r * 256;
      int row = id >> 3;
      int c4 = (id & 7) * 4;
      float4 xv = *(const float4*)(Xb + (size_t)row * Dc + d0 + c4);
      Xs[c4 + 0][row] = xv.x; Xs[c4 + 1][row] = xv.y;
      Xs[c4 + 2][row] = xv.z; Xs[c4 + 3][row] = xv.w;
      float4 wv = *(const float4*)(Wm + (size_t)row * Dc + d0 + c4);
      Ws[c4 + 0][row] = wv.x; Ws[c4 + 1][row] = wv.y;
      Ws[c4 + 2][row] = wv.z; Ws[c4 + 3][row] = wv.w;
    }
    __syncthreads();
    #pragma unroll
    for (int d = 0; d < 32; ++d) {
      float a[8], w[8];
      *(float4*)&a[0] = *(const float4*)&Xs[d][ty * 8];
      *(float4*)&a[4] = *(const float4*)&Xs[d][ty * 8 + 4];
      *(float4*)&w[0] = *(const float4*)&Ws[d][tx * 8];
      *(float4*)&w[4] = *(const float4*)&Ws[d][tx * 8 + 4];
      #pragma unroll
      for (int i = 0; i < 8; ++i)
        #pragma unroll
        for (int j = 0; j < 8; ++j)
          acc[i][j] += a[i] * w[j];
    }
    __syncthreads();
  }

  #pragma unroll
  for (int j = 0; j < 8; ++j) {
    int l = tx * 8 + j;
    float* dst = sl + ((size_t)bloc * Lc + l) * Nc + nbase + ty * 8;
    float4 o0 = make_float4(acc[0][j], acc[1][j], acc[2][j], acc[3][j]);
    float4 o1 = make_float4(acc[4][j], acc[5][j], acc[6][j], acc[7][j]);
    *(float4*)dst = o0;
    *(float4*)(dst + 4) = o1;
  }
}

// ---------------------------------------------------------------------------
// Kernel 4: radix-rank "sort" + dot (v2).
//  - single pref array: hist -> exclusive prefix -> (atomic-bump scatter)
//    leaves inclusive prefix; rank segment = [pref[b-1], pref[b])
//  - skey reused for sorted output after the rank pass
//  - XOR-swizzled histogram layout so the stride-16 scan phase is
//    bank-conflict-free
//  LDS = 16K(pref) + 16K(skey) -> 4 blocks/CU (was 3).
// ---------------------------------------------------------------------------
__device__ __forceinline__ int swz(int i) { return i ^ ((i >> 4) & 31); }

__global__ __launch_bounds__(256, 4) void rank_dot_kernel(
    const float* __restrict__ sl, const float* __restrict__ v,
    const float* __restrict__ C, float* __restrict__ out, int b0) {
  constexpr int NB = 4096;
  constexpr float LO = -6.0f;
  constexpr float SCALE = (float)NB / 12.0f;

  __shared__ int pref[NB];       // hist -> excl prefix -> incl prefix
  __shared__ float skey[Nc];     // bin-ordered keys; then sorted values
  __shared__ int wsum[4];
  __shared__ float red[4];

  int l = blockIdx.x & (Lc - 1);
  int bloc = blockIdx.x >> 7;
  int tid = threadIdx.x;
  const float* src = sl + ((size_t)bloc * Lc + l) * Nc;

  // load this thread's 16 contiguous elements
  float x[16];
  {
    const float4* s4 = (const float4*)src;
    #pragma unroll
    for (int j = 0; j < 4; ++j) {
      float4 f = s4[tid * 4 + j];
      x[j * 4 + 0] = f.x; x[j * 4 + 1] = f.y;
      x[j * 4 + 2] = f.z; x[j * 4 + 3] = f.w;
    }
  }

  for (int i = tid; i < NB; i += 256) pref[i] = 0;
  __syncthreads();

  // histogram (swizzled layout)
  int bb[16];
  #pragma unroll
  for (int j = 0; j < 16; ++j) {
    int bi = (int)((x[j] - LO) * SCALE);
    bi = bi < 0 ? 0 : (bi > NB - 1 ? NB - 1 : bi);
    bb[j] = bi;
    atomicAdd(&pref[swz(bi)], 1);
  }
  __syncthreads();

  // exclusive prefix sum over 4096 logical bins
  {
    int base_ = tid * 16;
    int loc[16]; int s = 0;
    #pragma unroll
    for (int j = 0; j < 16; ++j) loc[j] = pref[swz(base_ + j)];
    #pragma unroll
    for (int j = 0; j < 16; ++j) { int c = loc[j]; loc[j] = s; s += c; }
    int lane = tid & 63, wv = tid >> 6;
    int inc = s;
    #pragma unroll
    for (int off = 1; off < 64; off <<= 1) {
      int o = __shfl_up(inc, off, 64);
      if (lane >= off) inc += o;
    }
    if (lane == 63) wsum[wv] = inc;
    __syncthreads();
    int wbase = 0;
    #pragma unroll
    for (int w = 0; w < 4; ++w) if (w < wv) wbase += wsum[w];
    int tbase = wbase + inc - s;  // exclusive across threads
    #pragma unroll
    for (int j = 0; j < 16; ++j) pref[swz(base_ + j)] = tbase + loc[j];
  }
  __syncthreads();

  // scatter into bin-ordered array; pref[b] becomes inclusive end of bin b
  int pp[16];
  #pragma unroll
  for (int j = 0; j < 16; ++j) {
    int p = atomicAdd(&pref[swz(bb[j])], 1);
    pp[j] = p;
    skey[p] = x[j];
  }
  __syncthreads();

  // exact rank within bin segment (tie-break by scatter position; ties are
  // equal values so the sorted array is order-independent)
  int rr[16];
  #pragma unroll
  for (int j = 0; j < 16; ++j) {
    int b = bb[j];
    int lo_ = b ? pref[swz(b - 1)] : 0;
    int hi_ = pref[swz(b)];
    float xx = x[j];
    int myp = pp[j];
    int r = lo_;
    for (int q = lo_; q < hi_; ++q) {
      float y = skey[q];
      r += (y < xx || (y == xx && q < myp)) ? 1 : 0;
    }
    rr[j] = r;
  }
  __syncthreads();

  // skey is dead -> write sorted values into it
  #pragma unroll
  for (int j = 0; j < 16; ++j) skey[rr[j]] = x[j];
  __syncthreads();

  // coalesced dot with v row
  const float4* v4 = (const float4*)(v + (size_t)l * Nc);
  const float4* sv4 = (const float4*)skey;
  float acc = 0.f;
  for (int i = tid; i < Nc / 4; i += 256) {
    float4 a = sv4[i], w = v4[i];
    acc += a.x * w.x + a.y * w.y + a.z * w.z + a.w * w.w;
  }
  #pragma unroll
  for (int off = 1; off < 64; off <<= 1) acc += __shfl_xor(acc, off, 64);
  if ((tid & 63) == 0) red[tid >> 6] = acc;
  __syncthreads();
  if (tid == 0) {
    int b = b0 + bloc;
    out[(size_t)b * Lc + l] = C[l] - (red[0] + red[1] + red[2] + red[3]);
  }
}

// ---------------------------------------------------------------------------
extern "C" void kernel_launch(void* const* d_in, const int* in_sizes, int n_in,
                              void* d_out, int out_size, void* d_ws, size_t ws_size,
                              hipStream_t stream) {
  const float* X       = (const float*)d_in[0];  // [B,N,D]
  const float* theta_v = (const float*)d_in[1];  // [L,D]
  const float* ref     = (const float*)d_in[2];  // [M,L]
  const float* weight  = (const float*)d_in[3];  // [L,M]
  float* out = (float*)d_out;                    // [B,L]

  // workspace layout: v [L*N] | W [L*D] | C [128] | sl [chunk*L*N]
  float* v  = (float*)d_ws;
  float* W  = v + (size_t)Lc * Nc;
  float* Cc = W + (size_t)Lc * Dc;
  float* sl = Cc + 128;
  size_t used = (size_t)((char*)sl - (char*)d_ws);
  size_t per_b = (size_t)Lc * Nc * sizeof(float);  // 2 MB per batch element
  int chunk = 1;
  if (ws_size > used + per_b) {
    size_t c = (ws_size - used) / per_b;
    chunk = (int)(c > (size_t)Bc ? (size_t)Bc : c);
    if (chunk < 1) chunk = 1;
  }

  prep_kernel<<<Lc, 128, 0, stream>>>(theta_v, ref, weight, W, Cc);
  build_v_kernel<<<Lc, 256, 0, stream>>>(ref, weight, v);

  for (int b0 = 0; b0 < Bc; b0 += chunk) {
    int nb = (Bc - b0) < chunk ? (Bc - b0) : chunk;
    dim3 g1(Nc / 128, nb);
    gemm_kernel<<<g1, 256, 0, stream>>>(X + (size_t)b0 * Nc * Dc, W, sl);
    rank_dot_kernel<<<(size_t)nb * Lc, 256, 0, stream>>>(sl, v, Cc, out, b0);
  }
}

// Round 4
// 267.030 us; speedup vs baseline: 2.3064x; 1.0932x over previous
//
#include <hip/hip_runtime.h>

// Problem constants
static constexpr int Bc = 64;     // batch
static constexpr int Nc = 4096;   // set size
static constexpr int Dc = 128;    // d_in
static constexpr int Mc = 1024;   // num ref points
static constexpr int Lc = 128;    // num projections

using short8 = __attribute__((ext_vector_type(8))) short;
using f32x4  = __attribute__((ext_vector_type(4))) float;

__device__ __forceinline__ unsigned short f2bf(float x) {
  unsigned u = __builtin_bit_cast(unsigned, x);
  return (unsigned short)((u + 0x7FFFu + ((u >> 16) & 1u)) >> 16);
}
__device__ __forceinline__ float bf2f(unsigned short h) {
  unsigned u = ((unsigned)h) << 16;
  return __builtin_bit_cast(float, u);
}

// ---------------------------------------------------------------------------
// Kernel 1: W = theta_v / ||row||, C[l] = sum_m ref[m,l]*weight[l,m]
// ---------------------------------------------------------------------------
__global__ __launch_bounds__(128) void prep_kernel(
    const float* __restrict__ theta_v, const float* __restrict__ ref,
    const float* __restrict__ weight, float* __restrict__ W,
    float* __restrict__ C) {
  int l = blockIdx.x;
  int tid = threadIdx.x;  // 0..127 == d
  float w = theta_v[l * Dc + tid];
  float sq = w * w;
  #pragma unroll
  for (int off = 1; off < 64; off <<= 1) sq += __shfl_xor(sq, off, 64);
  __shared__ float s2[2];
  if ((tid & 63) == 0) s2[tid >> 6] = sq;
  __syncthreads();
  float norm = sqrtf(s2[0] + s2[1]);
  W[l * Dc + tid] = w / norm;

  float acc = 0.f;
  for (int m = tid; m < Mc; m += 128) acc += ref[(size_t)m * Lc + l] * weight[(size_t)l * Mc + m];
  #pragma unroll
  for (int off = 1; off < 64; off <<= 1) acc += __shfl_xor(acc, off, 64);
  __shared__ float c2[2];
  if ((tid & 63) == 0) c2[tid >> 6] = acc;
  __syncthreads();
  if (tid == 0) C[l] = c2[0] + c2[1];
}

// ---------------------------------------------------------------------------
// Kernel 2: build v[l][n] (stable argsort of ref column + interp stencil scatter)
// ---------------------------------------------------------------------------
__global__ __launch_bounds__(256) void build_v_kernel(
    const float* __restrict__ ref, const float* __restrict__ weight,
    float* __restrict__ v) {
  int l = blockIdx.x;
  int tid = threadIdx.x;
  __shared__ float key[Mc];
  __shared__ int idx[Mc];
  __shared__ float vrow[Nc];

  for (int m = tid; m < Mc; m += 256) {
    key[m] = ref[(size_t)m * Lc + l];
    idx[m] = m;
  }
  for (int i = tid; i < Nc; i += 256) vrow[i] = 0.f;
  __syncthreads();

  // stable bitonic sort ascending by (key, idx)
  for (int k = 2; k <= Mc; k <<= 1) {
    for (int j = k >> 1; j > 0; j >>= 1) {
      for (int t = tid; t < Mc / 2; t += 256) {
        int i = ((t & ~(j - 1)) << 1) | (t & (j - 1));
        int p = i | j;
        bool up = ((i & k) == 0);
        float a = key[i], b = key[p];
        int ia = idx[i], ib = idx[p];
        bool agt = (a > b) || (a == b && ia > ib);
        if (agt == up) {
          key[i] = b; key[p] = a;
          idx[i] = ib; idx[p] = ia;
        }
      }
      __syncthreads();
    }
  }

  for (int r = tid; r < Mc; r += 256) {
    float wv = weight[(size_t)l * Mc + r];  // weight[l, rank]
    int orig = idx[r];
    double pos = (double)(orig + 1) * (double)(Nc + 1) / (double)(Mc + 1) - 1.0;
    int i0 = (int)pos;
    float t = (float)(pos - (double)i0);
    atomicAdd(&vrow[i0], (1.0f - t) * wv);
    atomicAdd(&vrow[i0 + 1], t * wv);
  }
  __syncthreads();
  for (int i = tid; i < Nc; i += 256) v[(size_t)l * Nc + i] = vrow[i];
}

// ---------------------------------------------------------------------------
// Kernel 3 (v2): MFMA GEMM with f32 = bf16 hi + bf16 lo split (3-term).
// sl[bloc][l][n] = sum_d X[bloc,n,d] * W[l,d]
// grid = (N/128, nb), 256 threads (4 waves). Block tile: 128n x 128l, BK=32.
// Wave w owns n-rows [w*32, w*32+32) x all 128 l.
// MFMA 16x16x32 bf16: A lane&15 = n-row, B lane&15 = l-col, k=(lane>>4)*8+j;
// C/D: col = lane&15 (l), row = (lane>>4)*4 + reg (n).   [m89/m97 verified]
// ---------------------------------------------------------------------------
__global__ __launch_bounds__(256) void gemm_kernel(
    const float* __restrict__ X, const float* __restrict__ Wm,
    float* __restrict__ sl) {
  // padded rows: 32 d + 8 pad = 40 shorts = 80 B stride (16B-aligned rows)
  __shared__ unsigned short Ah[128][40];
  __shared__ unsigned short Al[128][40];
  __shared__ unsigned short Bh[128][40];
  __shared__ unsigned short Bl[128][40];

  int bloc = blockIdx.y;
  int nbase = blockIdx.x * 128;
  const float* Xb = X + ((size_t)bloc * Nc + nbase) * Dc;
  int tid = threadIdx.x;
  int lane = tid & 63;
  int w = tid >> 6;
  int m16 = lane & 15;
  int kg = lane >> 4;

  f32x4 acc[2][8] = {};

  for (int d0 = 0; d0 < Dc; d0 += 32) {
    __syncthreads();  // previous chunk's LDS reads done
    #pragma unroll
    for (int r = 0; r < 4; ++r) {
      int id = tid + r * 256;      // 0..1023
      int row = id >> 3;           // 0..127
      int c4 = (id & 7) * 4;       // 0..28
      float4 xv = *(const float4*)(Xb + (size_t)row * Dc + d0 + c4);
      ushort4 hi, lo;
      hi.x = f2bf(xv.x); lo.x = f2bf(xv.x - bf2f(hi.x));
      hi.y = f2bf(xv.y); lo.y = f2bf(xv.y - bf2f(hi.y));
      hi.z = f2bf(xv.z); lo.z = f2bf(xv.z - bf2f(hi.z));
      hi.w = f2bf(xv.w); lo.w = f2bf(xv.w - bf2f(hi.w));
      *(ushort4*)&Ah[row][c4] = hi;
      *(ushort4*)&Al[row][c4] = lo;
      float4 wv = *(const float4*)(Wm + (size_t)row * Dc + d0 + c4);  // row == l
      hi.x = f2bf(wv.x); lo.x = f2bf(wv.x - bf2f(hi.x));
      hi.y = f2bf(wv.y); lo.y = f2bf(wv.y - bf2f(hi.y));
      hi.z = f2bf(wv.z); lo.z = f2bf(wv.z - bf2f(hi.z));
      hi.w = f2bf(wv.w); lo.w = f2bf(wv.w - bf2f(hi.w));
      *(ushort4*)&Bh[row][c4] = hi;
      *(ushort4*)&Bl[row][c4] = lo;
    }
    __syncthreads();

    short8 ah[2], al[2];
    #pragma unroll
    for (int t = 0; t < 2; ++t) {
      ah[t] = *(const short8*)&Ah[w * 32 + t * 16 + m16][kg * 8];
      al[t] = *(const short8*)&Al[w * 32 + t * 16 + m16][kg * 8];
    }
    #pragma unroll
    for (int u = 0; u < 8; ++u) {
      short8 bh = *(const short8*)&Bh[u * 16 + m16][kg * 8];
      short8 bl = *(const short8*)&Bl[u * 16 + m16][kg * 8];
      #pragma unroll
      for (int t = 0; t < 2; ++t) {
        acc[t][u] = __builtin_amdgcn_mfma_f32_16x16x32_bf16(ah[t], bh, acc[t][u], 0, 0, 0);
        acc[t][u] = __builtin_amdgcn_mfma_f32_16x16x32_bf16(ah[t], bl, acc[t][u], 0, 0, 0);
        acc[t][u] = __builtin_amdgcn_mfma_f32_16x16x32_bf16(al[t], bh, acc[t][u], 0, 0, 0);
      }
    }
  }

  // write-out: per (t,u): rows n0..n0+3 contiguous for fixed l -> float4
  #pragma unroll
  for (int t = 0; t < 2; ++t) {
    #pragma unroll
    for (int u = 0; u < 8; ++u) {
      int l = u * 16 + m16;
      int n0 = nbase + w * 32 + t * 16 + kg * 4;
      float* dst = sl + ((size_t)bloc * Lc + l) * Nc + n0;
      *(float4*)dst = *(float4*)&acc[t][u];
    }
  }
}

// ---------------------------------------------------------------------------
// Kernel 4 (v3): radix-rank + dot.
//  - LDS exactly 32 KB (wsum aliased into skey, red aliased into pref)
//    -> 5 blocks/CU
//  - strided element ownership: thread owns float4s {tid+256j} -> fully
//    coalesced global loads (ownership choice doesn't affect the sort)
// ---------------------------------------------------------------------------
__device__ __forceinline__ int swz(int i) { return i ^ ((i >> 4) & 31); }

__global__ __launch_bounds__(256, 5) void rank_dot_kernel(
    const float* __restrict__ sl, const float* __restrict__ v,
    const float* __restrict__ C, float* __restrict__ out, int b0) {
  constexpr int NB = 4096;
  constexpr float LO = -6.0f;
  constexpr float SCALE = (float)NB / 12.0f;

  __shared__ int pref[NB];       // hist -> excl prefix -> incl prefix; then red
  __shared__ float skey[Nc];     // (wsum during scan) bin-ordered keys; then sorted
  int* wsum = (int*)skey;        // live only during scan (before skey writes)
  float* red = (float*)pref;     // live only after last pref read (2 barriers)

  int l = blockIdx.x & (Lc - 1);
  int bloc = blockIdx.x >> 7;
  int tid = threadIdx.x;
  const float* src = sl + ((size_t)bloc * Lc + l) * Nc;

  // coalesced strided load: thread owns float4s {tid + 256*j}
  float x[16];
  {
    const float4* s4 = (const float4*)src;
    #pragma unroll
    for (int j = 0; j < 4; ++j) {
      float4 f = s4[tid + 256 * j];
      x[j * 4 + 0] = f.x; x[j * 4 + 1] = f.y;
      x[j * 4 + 2] = f.z; x[j * 4 + 3] = f.w;
    }
  }

  for (int i = tid; i < NB; i += 256) pref[i] = 0;
  __syncthreads();

  // histogram (swizzled layout)
  int bb[16];
  #pragma unroll
  for (int j = 0; j < 16; ++j) {
    int bi = (int)((x[j] - LO) * SCALE);
    bi = bi < 0 ? 0 : (bi > NB - 1 ? NB - 1 : bi);
    bb[j] = bi;
    atomicAdd(&pref[swz(bi)], 1);
  }
  __syncthreads();

  // exclusive prefix sum over 4096 logical bins
  {
    int base_ = tid * 16;
    int loc[16]; int s = 0;
    #pragma unroll
    for (int j = 0; j < 16; ++j) loc[j] = pref[swz(base_ + j)];
    #pragma unroll
    for (int j = 0; j < 16; ++j) { int c = loc[j]; loc[j] = s; s += c; }
    int lane = tid & 63, wv = tid >> 6;
    int inc = s;
    #pragma unroll
    for (int off = 1; off < 64; off <<= 1) {
      int o = __shfl_up(inc, off, 64);
      if (lane >= off) inc += o;
    }
    if (lane == 63) wsum[wv] = inc;
    __syncthreads();
    int wbase = 0;
    #pragma unroll
    for (int ww = 0; ww < 4; ++ww) if (ww < wv) wbase += wsum[ww];
    int tbase = wbase + inc - s;  // exclusive across threads
    #pragma unroll
    for (int j = 0; j < 16; ++j) pref[swz(base_ + j)] = tbase + loc[j];
  }
  __syncthreads();

  // scatter into bin-ordered array; pref[b] becomes inclusive end of bin b
  int pp[16];
  #pragma unroll
  for (int j = 0; j < 16; ++j) {
    int p = atomicAdd(&pref[swz(bb[j])], 1);
    pp[j] = p;
    skey[p] = x[j];
  }
  __syncthreads();

  // exact rank within bin segment (tie-break by scatter position; ties are
  // equal values so the sorted array is order-independent -> deterministic)
  int rr[16];
  #pragma unroll
  for (int j = 0; j < 16; ++j) {
    int b = bb[j];
    int lo_ = b ? pref[swz(b - 1)] : 0;
    int hi_ = pref[swz(b)];
    float xx = x[j];
    int myp = pp[j];
    int r = lo_;
    for (int q = lo_; q < hi_; ++q) {
      float y = skey[q];
      r += (y < xx || (y == xx && q < myp)) ? 1 : 0;
    }
    rr[j] = r;
  }
  __syncthreads();

  // skey is dead -> write sorted values into it
  #pragma unroll
  for (int j = 0; j < 16; ++j) skey[rr[j]] = x[j];
  __syncthreads();

  // coalesced dot with v row
  const float4* v4 = (const float4*)(v + (size_t)l * Nc);
  const float4* sv4 = (const float4*)skey;
  float acc = 0.f;
  for (int i = tid; i < Nc / 4; i += 256) {
    float4 a = sv4[i], w = v4[i];
    acc += a.x * w.x + a.y * w.y + a.z * w.z + a.w * w.w;
  }
  #pragma unroll
  for (int off = 1; off < 64; off <<= 1) acc += __shfl_xor(acc, off, 64);
  if ((tid & 63) == 0) red[tid >> 6] = acc;
  __syncthreads();
  if (tid == 0) {
    int b = b0 + bloc;
    out[(size_t)b * Lc + l] = C[l] - (red[0] + red[1] + red[2] + red[3]);
  }
}

// ---------------------------------------------------------------------------
extern "C" void kernel_launch(void* const* d_in, const int* in_sizes, int n_in,
                              void* d_out, int out_size, void* d_ws, size_t ws_size,
                              hipStream_t stream) {
  const float* X       = (const float*)d_in[0];  // [B,N,D]
  const float* theta_v = (const float*)d_in[1];  // [L,D]
  const float* ref     = (const float*)d_in[2];  // [M,L]
  const float* weight  = (const float*)d_in[3];  // [L,M]
  float* out = (float*)d_out;                    // [B,L]

  // workspace layout: v [L*N] | W [L*D] | C [128] | sl [chunk*L*N]
  float* v  = (float*)d_ws;
  float* W  = v + (size_t)Lc * Nc;
  float* Cc = W + (size_t)Lc * Dc;
  float* sl = Cc + 128;
  size_t used = (size_t)((char*)sl - (char*)d_ws);
  size_t per_b = (size_t)Lc * Nc * sizeof(float);  // 2 MB per batch element
  int chunk = 1;
  if (ws_size > used + per_b) {
    size_t c = (ws_size - used) / per_b;
    chunk = (int)(c > (size_t)Bc ? (size_t)Bc : c);
    if (chunk < 1) chunk = 1;
  }

  prep_kernel<<<Lc, 128, 0, stream>>>(theta_v, ref, weight, W, Cc);
  build_v_kernel<<<Lc, 256, 0, stream>>>(ref, weight, v);

  for (int b0 = 0; b0 < Bc; b0 += chunk) {
    int nb = (Bc - b0) < chunk ? (Bc - b0) : chunk;
    dim3 g1(Nc / 128, nb);
    gemm_kernel<<<g1, 256, 0, stream>>>(X + (size_t)b0 * Nc * Dc, W, sl);
    rank_dot_kernel<<<(size_t)nb * Lc, 256, 0, stream>>>(sl, v, Cc, out, b0);
  }
}

// Round 5
// 236.090 us; speedup vs baseline: 2.6086x; 1.1311x over previous
//
#include <hip/hip_runtime.h>

// Problem constants
static constexpr int Bc = 64;     // batch
static constexpr int Nc = 4096;   // set size
static constexpr int Dc = 128;    // d_in
static constexpr int Mc = 1024;   // num ref points
static constexpr int Lc = 128;    // num projections

using short8 = __attribute__((ext_vector_type(8))) short;
using f32x4  = __attribute__((ext_vector_type(4))) float;

__device__ __forceinline__ unsigned short f2bf(float x) {
  unsigned u = __builtin_bit_cast(unsigned, x);
  return (unsigned short)((u + 0x7FFFu + ((u >> 16) & 1u)) >> 16);
}
__device__ __forceinline__ float bf2f(unsigned short h) {
  unsigned u = ((unsigned)h) << 16;
  return __builtin_bit_cast(float, u);
}

// ---------------------------------------------------------------------------
// Kernel 1: W = theta_v / ||row||, C[l] = sum_m ref[m,l]*weight[l,m]
// ---------------------------------------------------------------------------
__global__ __launch_bounds__(128) void prep_kernel(
    const float* __restrict__ theta_v, const float* __restrict__ ref,
    const float* __restrict__ weight, float* __restrict__ W,
    float* __restrict__ C) {
  int l = blockIdx.x;
  int tid = threadIdx.x;  // 0..127 == d
  float w = theta_v[l * Dc + tid];
  float sq = w * w;
  #pragma unroll
  for (int off = 1; off < 64; off <<= 1) sq += __shfl_xor(sq, off, 64);
  __shared__ float s2[2];
  if ((tid & 63) == 0) s2[tid >> 6] = sq;
  __syncthreads();
  float norm = sqrtf(s2[0] + s2[1]);
  W[l * Dc + tid] = w / norm;

  float acc = 0.f;
  for (int m = tid; m < Mc; m += 128) acc += ref[(size_t)m * Lc + l] * weight[(size_t)l * Mc + m];
  #pragma unroll
  for (int off = 1; off < 64; off <<= 1) acc += __shfl_xor(acc, off, 64);
  __shared__ float c2[2];
  if ((tid & 63) == 0) c2[tid >> 6] = acc;
  __syncthreads();
  if (tid == 0) C[l] = c2[0] + c2[1];
}

// ---------------------------------------------------------------------------
// Kernel 2: build v[l][n] (stable argsort of ref column + interp stencil scatter)
// ---------------------------------------------------------------------------
__global__ __launch_bounds__(256) void build_v_kernel(
    const float* __restrict__ ref, const float* __restrict__ weight,
    float* __restrict__ v) {
  int l = blockIdx.x;
  int tid = threadIdx.x;
  __shared__ float key[Mc];
  __shared__ int idx[Mc];
  __shared__ float vrow[Nc];

  for (int m = tid; m < Mc; m += 256) {
    key[m] = ref[(size_t)m * Lc + l];
    idx[m] = m;
  }
  for (int i = tid; i < Nc; i += 256) vrow[i] = 0.f;
  __syncthreads();

  // stable bitonic sort ascending by (key, idx)
  for (int k = 2; k <= Mc; k <<= 1) {
    for (int j = k >> 1; j > 0; j >>= 1) {
      for (int t = tid; t < Mc / 2; t += 256) {
        int i = ((t & ~(j - 1)) << 1) | (t & (j - 1));
        int p = i | j;
        bool up = ((i & k) == 0);
        float a = key[i], b = key[p];
        int ia = idx[i], ib = idx[p];
        bool agt = (a > b) || (a == b && ia > ib);
        if (agt == up) {
          key[i] = b; key[p] = a;
          idx[i] = ib; idx[p] = ia;
        }
      }
      __syncthreads();
    }
  }

  for (int r = tid; r < Mc; r += 256) {
    float wv = weight[(size_t)l * Mc + r];  // weight[l, rank]
    int orig = idx[r];
    double pos = (double)(orig + 1) * (double)(Nc + 1) / (double)(Mc + 1) - 1.0;
    int i0 = (int)pos;
    float t = (float)(pos - (double)i0);
    atomicAdd(&vrow[i0], (1.0f - t) * wv);
    atomicAdd(&vrow[i0 + 1], t * wv);
  }
  __syncthreads();
  for (int i = tid; i < Nc; i += 256) v[(size_t)l * Nc + i] = vrow[i];
}

// ---------------------------------------------------------------------------
// Kernel 3: MFMA GEMM with f32 = bf16 hi + bf16 lo split (3-term).
// sl[bloc][l][n] = sum_d X[bloc,n,d] * W[l,d]
// ---------------------------------------------------------------------------
__global__ __launch_bounds__(256) void gemm_kernel(
    const float* __restrict__ X, const float* __restrict__ Wm,
    float* __restrict__ sl) {
  __shared__ unsigned short Ah[128][40];
  __shared__ unsigned short Al[128][40];
  __shared__ unsigned short Bh[128][40];
  __shared__ unsigned short Bl[128][40];

  int bloc = blockIdx.y;
  int nbase = blockIdx.x * 128;
  const float* Xb = X + ((size_t)bloc * Nc + nbase) * Dc;
  int tid = threadIdx.x;
  int lane = tid & 63;
  int w = tid >> 6;
  int m16 = lane & 15;
  int kg = lane >> 4;

  f32x4 acc[2][8] = {};

  for (int d0 = 0; d0 < Dc; d0 += 32) {
    __syncthreads();
    #pragma unroll
    for (int r = 0; r < 4; ++r) {
      int id = tid + r * 256;
      int row = id >> 3;
      int c4 = (id & 7) * 4;
      float4 xv = *(const float4*)(Xb + (size_t)row * Dc + d0 + c4);
      ushort4 hi, lo;
      hi.x = f2bf(xv.x); lo.x = f2bf(xv.x - bf2f(hi.x));
      hi.y = f2bf(xv.y); lo.y = f2bf(xv.y - bf2f(hi.y));
      hi.z = f2bf(xv.z); lo.z = f2bf(xv.z - bf2f(hi.z));
      hi.w = f2bf(xv.w); lo.w = f2bf(xv.w - bf2f(hi.w));
      *(ushort4*)&Ah[row][c4] = hi;
      *(ushort4*)&Al[row][c4] = lo;
      float4 wv = *(const float4*)(Wm + (size_t)row * Dc + d0 + c4);
      hi.x = f2bf(wv.x); lo.x = f2bf(wv.x - bf2f(hi.x));
      hi.y = f2bf(wv.y); lo.y = f2bf(wv.y - bf2f(hi.y));
      hi.z = f2bf(wv.z); lo.z = f2bf(wv.z - bf2f(hi.z));
      hi.w = f2bf(wv.w); lo.w = f2bf(wv.w - bf2f(hi.w));
      *(ushort4*)&Bh[row][c4] = hi;
      *(ushort4*)&Bl[row][c4] = lo;
    }
    __syncthreads();

    short8 ah[2], al[2];
    #pragma unroll
    for (int t = 0; t < 2; ++t) {
      ah[t] = *(const short8*)&Ah[w * 32 + t * 16 + m16][kg * 8];
      al[t] = *(const short8*)&Al[w * 32 + t * 16 + m16][kg * 8];
    }
    #pragma unroll
    for (int u = 0; u < 8; ++u) {
      short8 bh = *(const short8*)&Bh[u * 16 + m16][kg * 8];
      short8 bl = *(const short8*)&Bl[u * 16 + m16][kg * 8];
      #pragma unroll
      for (int t = 0; t < 2; ++t) {
        acc[t][u] = __builtin_amdgcn_mfma_f32_16x16x32_bf16(ah[t], bh, acc[t][u], 0, 0, 0);
        acc[t][u] = __builtin_amdgcn_mfma_f32_16x16x32_bf16(ah[t], bl, acc[t][u], 0, 0, 0);
        acc[t][u] = __builtin_amdgcn_mfma_f32_16x16x32_bf16(al[t], bh, acc[t][u], 0, 0, 0);
      }
    }
  }

  #pragma unroll
  for (int t = 0; t < 2; ++t) {
    #pragma unroll
    for (int u = 0; u < 8; ++u) {
      int l = u * 16 + m16;
      int n0 = nbase + w * 32 + t * 16 + kg * 4;
      float* dst = sl + ((size_t)bloc * Lc + l) * Nc + n0;
      *(float4*)dst = *(float4*)&acc[t][u];
    }
  }
}

// ---------------------------------------------------------------------------
// Kernel 4 (v4): radix-rank + fused dot.
//  - position-ordered rank phase: thread ranks the value at scattered
//    position p (recomputing its bin from the value), tie-break by p.
//    Adjacent lanes -> adjacent positions -> near-equal segment lengths
//    (no divergence blowup) and broadcast-friendly segment reads.
//  - dot fused into rank phase via v_row gather (L2-resident row).
//  - bins over [-4.2, 4.2]: shorter segments, exact (clamped bins still
//    exactly ranked).
// ---------------------------------------------------------------------------
__device__ __forceinline__ int swz(int i) { return i ^ ((i >> 4) & 31); }

__global__ __launch_bounds__(256, 5) void rank_dot_kernel(
    const float* __restrict__ sl, const float* __restrict__ v,
    const float* __restrict__ C, float* __restrict__ out, int b0) {
  constexpr int NB = 4096;
  constexpr float LO = -4.2f;
  constexpr float SCALE = (float)NB / 8.4f;

  __shared__ int pref[NB];       // hist -> excl prefix -> incl prefix; then red
  __shared__ float skey[Nc];     // (wsum during scan) bin-ordered keys
  int* wsum = (int*)skey;        // live only during scan (before skey writes)
  float* red = (float*)pref;     // live only after final barrier

  int l = blockIdx.x & (Lc - 1);
  int bloc = blockIdx.x >> 7;
  int tid = threadIdx.x;
  const float* src = sl + ((size_t)bloc * Lc + l) * Nc;

  // coalesced strided load: thread owns float4s {tid + 256*j}
  float x[16];
  {
    const float4* s4 = (const float4*)src;
    #pragma unroll
    for (int j = 0; j < 4; ++j) {
      float4 f = s4[tid + 256 * j];
      x[j * 4 + 0] = f.x; x[j * 4 + 1] = f.y;
      x[j * 4 + 2] = f.z; x[j * 4 + 3] = f.w;
    }
  }

  for (int i = tid; i < NB; i += 256) pref[i] = 0;
  __syncthreads();

  // histogram (swizzled layout)
  int bb[16];
  #pragma unroll
  for (int j = 0; j < 16; ++j) {
    int bi = (int)((x[j] - LO) * SCALE);
    bi = bi < 0 ? 0 : (bi > NB - 1 ? NB - 1 : bi);
    bb[j] = bi;
    atomicAdd(&pref[swz(bi)], 1);
  }
  __syncthreads();

  // exclusive prefix sum over 4096 logical bins
  {
    int base_ = tid * 16;
    int loc[16]; int s = 0;
    #pragma unroll
    for (int j = 0; j < 16; ++j) loc[j] = pref[swz(base_ + j)];
    #pragma unroll
    for (int j = 0; j < 16; ++j) { int c = loc[j]; loc[j] = s; s += c; }
    int lane = tid & 63, wv = tid >> 6;
    int inc = s;
    #pragma unroll
    for (int off = 1; off < 64; off <<= 1) {
      int o = __shfl_up(inc, off, 64);
      if (lane >= off) inc += o;
    }
    if (lane == 63) wsum[wv] = inc;
    __syncthreads();
    int wbase = 0;
    #pragma unroll
    for (int ww = 0; ww < 4; ++ww) if (ww < wv) wbase += wsum[ww];
    int tbase = wbase + inc - s;  // exclusive across threads
    #pragma unroll
    for (int j = 0; j < 16; ++j) pref[swz(base_ + j)] = tbase + loc[j];
  }
  __syncthreads();

  // scatter into bin-ordered array; pref[b] becomes inclusive end of bin b
  #pragma unroll
  for (int j = 0; j < 16; ++j) {
    int p = atomicAdd(&pref[swz(bb[j])], 1);
    skey[p] = x[j];
  }
  __syncthreads();

  // position-ordered rank + fused dot. Position p's value y: recompute its
  // bin (pure function of y -> consistent with histogram), rank within the
  // segment with tie-break by position (p IS the scatter position; ties are
  // bitwise-equal values so the result is deterministic).
  const float* vrow = v + (size_t)l * Nc;
  float acc = 0.f;
  #pragma unroll
  for (int k = 0; k < 16; ++k) {
    int p = tid + 256 * k;
    float y = skey[p];
    int b = (int)((y - LO) * SCALE);
    b = b < 0 ? 0 : (b > NB - 1 ? NB - 1 : b);
    int lo_ = b ? pref[swz(b - 1)] : 0;
    int hi_ = pref[swz(b)];
    int r = lo_;
    for (int q = lo_; q < hi_; ++q) {
      float z = skey[q];
      r += (z < y || (z == y && q < p)) ? 1 : 0;
    }
    acc += y * vrow[r];
  }

  #pragma unroll
  for (int off = 1; off < 64; off <<= 1) acc += __shfl_xor(acc, off, 64);
  __syncthreads();  // all pref reads done before red (aliased) is written
  if ((tid & 63) == 0) red[tid >> 6] = acc;
  __syncthreads();
  if (tid == 0) {
    int b = b0 + bloc;
    out[(size_t)b * Lc + l] = C[l] - (red[0] + red[1] + red[2] + red[3]);
  }
}

// ---------------------------------------------------------------------------
extern "C" void kernel_launch(void* const* d_in, const int* in_sizes, int n_in,
                              void* d_out, int out_size, void* d_ws, size_t ws_size,
                              hipStream_t stream) {
  const float* X       = (const float*)d_in[0];  // [B,N,D]
  const float* theta_v = (const float*)d_in[1];  // [L,D]
  const float* ref     = (const float*)d_in[2];  // [M,L]
  const float* weight  = (const float*)d_in[3];  // [L,M]
  float* out = (float*)d_out;                    // [B,L]

  // workspace layout: v [L*N] | W [L*D] | C [128] | sl [chunk*L*N]
  float* v  = (float*)d_ws;
  float* W  = v + (size_t)Lc * Nc;
  float* Cc = W + (size_t)Lc * Dc;
  float* sl = Cc + 128;
  size_t used = (size_t)((char*)sl - (char*)d_ws);
  size_t per_b = (size_t)Lc * Nc * sizeof(float);  // 2 MB per batch element
  int chunk = 1;
  if (ws_size > used + per_b) {
    size_t c = (ws_size - used) / per_b;
    chunk = (int)(c > (size_t)Bc ? (size_t)Bc : c);
    if (chunk < 1) chunk = 1;
  }
  // cap chunk so the sl chunk (~2 MB/b) stays L2/L3-resident between the
  // producing gemm and consuming rank_dot -> no HBM writeback contention
  if (chunk > 16) chunk = 16;

  prep_kernel<<<Lc, 128, 0, stream>>>(theta_v, ref, weight, W, Cc);
  build_v_kernel<<<Lc, 256, 0, stream>>>(ref, weight, v);

  for (int b0 = 0; b0 < Bc; b0 += chunk) {
    int nb = (Bc - b0) < chunk ? (Bc - b0) : chunk;
    dim3 g1(Nc / 128, nb);
    gemm_kernel<<<g1, 256, 0, stream>>>(X + (size_t)b0 * Nc * Dc, W, sl);
    rank_dot_kernel<<<(size_t)nb * Lc, 256, 0, stream>>>(sl, v, Cc, out, b0);
  }
}

// Round 6
// 207.029 us; speedup vs baseline: 2.9748x; 1.1404x over previous
//
#include <hip/hip_runtime.h>

// Problem constants
static constexpr int Bc = 64;     // batch
static constexpr int Nc = 4096;   // set size
static constexpr int Dc = 128;    // d_in
static constexpr int Mc = 1024;   // num ref points
static constexpr int Lc = 128;    // num projections

using short8 = __attribute__((ext_vector_type(8))) short;
using f32x4  = __attribute__((ext_vector_type(4))) float;

__device__ __forceinline__ unsigned short f2bf(float x) {
  unsigned u = __builtin_bit_cast(unsigned, x);
  return (unsigned short)((u + 0x7FFFu + ((u >> 16) & 1u)) >> 16);
}
__device__ __forceinline__ float bf2f(unsigned short h) {
  unsigned u = ((unsigned)h) << 16;
  return __builtin_bit_cast(float, u);
}

// ---------------------------------------------------------------------------
// Kernel 1: W = theta_v/||row|| -> bf16 hi/lo split (precomputed for gemm);
//           C[l] = sum_m ref[m,l]*weight[l,m]
// ---------------------------------------------------------------------------
__global__ __launch_bounds__(128) void prep_kernel(
    const float* __restrict__ theta_v, const float* __restrict__ ref,
    const float* __restrict__ weight, unsigned short* __restrict__ Wh,
    unsigned short* __restrict__ Wl, float* __restrict__ C) {
  int l = blockIdx.x;
  int tid = threadIdx.x;  // 0..127 == d
  float w = theta_v[l * Dc + tid];
  float sq = w * w;
  #pragma unroll
  for (int off = 1; off < 64; off <<= 1) sq += __shfl_xor(sq, off, 64);
  __shared__ float s2[2];
  if ((tid & 63) == 0) s2[tid >> 6] = sq;
  __syncthreads();
  float norm = sqrtf(s2[0] + s2[1]);
  float val = w / norm;
  unsigned short hi = f2bf(val);
  Wh[l * Dc + tid] = hi;
  Wl[l * Dc + tid] = f2bf(val - bf2f(hi));

  float acc = 0.f;
  for (int m = tid; m < Mc; m += 128) acc += ref[(size_t)m * Lc + l] * weight[(size_t)l * Mc + m];
  #pragma unroll
  for (int off = 1; off < 64; off <<= 1) acc += __shfl_xor(acc, off, 64);
  __shared__ float c2[2];
  if ((tid & 63) == 0) c2[tid >> 6] = acc;
  __syncthreads();
  if (tid == 0) C[l] = c2[0] + c2[1];
}

// ---------------------------------------------------------------------------
// Kernel 2: build v[l][n] (stable argsort of ref column + interp stencil scatter)
// ---------------------------------------------------------------------------
__global__ __launch_bounds__(256) void build_v_kernel(
    const float* __restrict__ ref, const float* __restrict__ weight,
    float* __restrict__ v) {
  int l = blockIdx.x;
  int tid = threadIdx.x;
  __shared__ float key[Mc];
  __shared__ int idx[Mc];
  __shared__ float vrow[Nc];

  for (int m = tid; m < Mc; m += 256) {
    key[m] = ref[(size_t)m * Lc + l];
    idx[m] = m;
  }
  for (int i = tid; i < Nc; i += 256) vrow[i] = 0.f;
  __syncthreads();

  // stable bitonic sort ascending by (key, idx)
  for (int k = 2; k <= Mc; k <<= 1) {
    for (int j = k >> 1; j > 0; j >>= 1) {
      for (int t = tid; t < Mc / 2; t += 256) {
        int i = ((t & ~(j - 1)) << 1) | (t & (j - 1));
        int p = i | j;
        bool up = ((i & k) == 0);
        float a = key[i], b = key[p];
        int ia = idx[i], ib = idx[p];
        bool agt = (a > b) || (a == b && ia > ib);
        if (agt == up) {
          key[i] = b; key[p] = a;
          idx[i] = ib; idx[p] = ia;
        }
      }
      __syncthreads();
    }
  }

  for (int r = tid; r < Mc; r += 256) {
    float wv = weight[(size_t)l * Mc + r];  // weight[l, rank]
    int orig = idx[r];
    double pos = (double)(orig + 1) * (double)(Nc + 1) / (double)(Mc + 1) - 1.0;
    int i0 = (int)pos;
    float t = (float)(pos - (double)i0);
    atomicAdd(&vrow[i0], (1.0f - t) * wv);
    atomicAdd(&vrow[i0 + 1], t * wv);
  }
  __syncthreads();
  for (int i = tid; i < Nc; i += 256) v[(size_t)l * Nc + i] = vrow[i];
}

// ---------------------------------------------------------------------------
// Kernel 3: MFMA GEMM, f32 = bf16 hi + lo (3-term). B-side pre-converted.
// sl[bloc][l][n] = sum_d X[bloc,n,d] * W[l,d]
// ---------------------------------------------------------------------------
__global__ __launch_bounds__(256) void gemm_kernel(
    const float* __restrict__ X, const unsigned short* __restrict__ Whp,
    const unsigned short* __restrict__ Wlp, float* __restrict__ sl) {
  __shared__ unsigned short Ah[128][40];
  __shared__ unsigned short Al[128][40];
  __shared__ unsigned short Bh[128][40];
  __shared__ unsigned short Bl[128][40];

  int bloc = blockIdx.y;
  int nbase = blockIdx.x * 128;
  const float* Xb = X + ((size_t)bloc * Nc + nbase) * Dc;
  int tid = threadIdx.x;
  int lane = tid & 63;
  int w = tid >> 6;
  int m16 = lane & 15;
  int kg = lane >> 4;

  f32x4 acc[2][8] = {};

  for (int d0 = 0; d0 < Dc; d0 += 32) {
    __syncthreads();
    #pragma unroll
    for (int r = 0; r < 4; ++r) {
      int id = tid + r * 256;
      int row = id >> 3;
      int c4 = (id & 7) * 4;
      float4 xv = *(const float4*)(Xb + (size_t)row * Dc + d0 + c4);
      ushort4 hi, lo;
      hi.x = f2bf(xv.x); lo.x = f2bf(xv.x - bf2f(hi.x));
      hi.y = f2bf(xv.y); lo.y = f2bf(xv.y - bf2f(hi.y));
      hi.z = f2bf(xv.z); lo.z = f2bf(xv.z - bf2f(hi.z));
      hi.w = f2bf(xv.w); lo.w = f2bf(xv.w - bf2f(hi.w));
      *(ushort4*)&Ah[row][c4] = hi;
      *(ushort4*)&Al[row][c4] = lo;
      // B side: precomputed bf16 hi/lo, pure copy
      *(ushort4*)&Bh[row][c4] = *(const ushort4*)(Whp + (size_t)row * Dc + d0 + c4);
      *(ushort4*)&Bl[row][c4] = *(const ushort4*)(Wlp + (size_t)row * Dc + d0 + c4);
    }
    __syncthreads();

    short8 ah[2], al[2];
    #pragma unroll
    for (int t = 0; t < 2; ++t) {
      ah[t] = *(const short8*)&Ah[w * 32 + t * 16 + m16][kg * 8];
      al[t] = *(const short8*)&Al[w * 32 + t * 16 + m16][kg * 8];
    }
    #pragma unroll
    for (int u = 0; u < 8; ++u) {
      short8 bh = *(const short8*)&Bh[u * 16 + m16][kg * 8];
      short8 bl = *(const short8*)&Bl[u * 16 + m16][kg * 8];
      #pragma unroll
      for (int t = 0; t < 2; ++t) {
        acc[t][u] = __builtin_amdgcn_mfma_f32_16x16x32_bf16(ah[t], bh, acc[t][u], 0, 0, 0);
        acc[t][u] = __builtin_amdgcn_mfma_f32_16x16x32_bf16(ah[t], bl, acc[t][u], 0, 0, 0);
        acc[t][u] = __builtin_amdgcn_mfma_f32_16x16x32_bf16(al[t], bh, acc[t][u], 0, 0, 0);
      }
    }
  }

  #pragma unroll
  for (int t = 0; t < 2; ++t) {
    #pragma unroll
    for (int u = 0; u < 8; ++u) {
      int l = u * 16 + m16;
      int n0 = nbase + w * 32 + t * 16 + kg * 4;
      float* dst = sl + ((size_t)bloc * Lc + l) * Nc + n0;
      *(float4*)dst = *(float4*)&acc[t][u];
    }
  }
}

// ---------------------------------------------------------------------------
// Kernel 5 (v5): radix-rank + fused dot, 512 threads (8 waves/block).
// 4 blocks/CU x 8 waves = 32 waves/CU (hw cap) to hide LDS/atomic latency.
// ---------------------------------------------------------------------------
__device__ __forceinline__ int swz(int i) { return i ^ ((i >> 4) & 31); }

__global__ __launch_bounds__(512, 8) void rank_dot_kernel(
    const float* __restrict__ sl, const float* __restrict__ v,
    const float* __restrict__ C, float* __restrict__ out, int b0) {
  constexpr int NB = 4096;
  constexpr float LO = -4.2f;
  constexpr float SCALE = (float)NB / 8.4f;
  constexpr int NT = 512;
  constexpr int EL = Nc / NT;  // 8 elements per thread

  __shared__ int pref[NB];       // hist -> excl prefix -> incl prefix; then red
  __shared__ float skey[Nc];     // (wsum during scan) bin-ordered keys
  int* wsum = (int*)skey;        // live only during scan (before skey writes)
  float* red = (float*)pref;     // live only after final barrier

  int l = blockIdx.x & (Lc - 1);
  int bloc = blockIdx.x >> 7;
  int tid = threadIdx.x;
  const float* src = sl + ((size_t)bloc * Lc + l) * Nc;

  // coalesced strided load: thread owns float4s {tid + 512*j}
  float x[EL];
  {
    const float4* s4 = (const float4*)src;
    #pragma unroll
    for (int j = 0; j < EL / 4; ++j) {
      float4 f = s4[tid + NT * j];
      x[j * 4 + 0] = f.x; x[j * 4 + 1] = f.y;
      x[j * 4 + 2] = f.z; x[j * 4 + 3] = f.w;
    }
  }

  for (int i = tid; i < NB; i += NT) pref[i] = 0;
  __syncthreads();

  // histogram (swizzled layout)
  int bb[EL];
  #pragma unroll
  for (int j = 0; j < EL; ++j) {
    int bi = (int)((x[j] - LO) * SCALE);
    bi = bi < 0 ? 0 : (bi > NB - 1 ? NB - 1 : bi);
    bb[j] = bi;
    atomicAdd(&pref[swz(bi)], 1);
  }
  __syncthreads();

  // exclusive prefix sum over 4096 logical bins (8 bins/thread)
  {
    int base_ = tid * 8;
    int loc[8]; int s = 0;
    #pragma unroll
    for (int j = 0; j < 8; ++j) loc[j] = pref[swz(base_ + j)];
    #pragma unroll
    for (int j = 0; j < 8; ++j) { int c = loc[j]; loc[j] = s; s += c; }
    int lane = tid & 63, wv = tid >> 6;
    int inc = s;
    #pragma unroll
    for (int off = 1; off < 64; off <<= 1) {
      int o = __shfl_up(inc, off, 64);
      if (lane >= off) inc += o;
    }
    if (lane == 63) wsum[wv] = inc;
    __syncthreads();
    int wbase = 0;
    #pragma unroll
    for (int ww = 0; ww < 8; ++ww) if (ww < wv) wbase += wsum[ww];
    int tbase = wbase + inc - s;  // exclusive across threads
    #pragma unroll
    for (int j = 0; j < 8; ++j) pref[swz(base_ + j)] = tbase + loc[j];
  }
  __syncthreads();

  // scatter into bin-ordered array; pref[b] becomes inclusive end of bin b
  #pragma unroll
  for (int j = 0; j < EL; ++j) {
    int p = atomicAdd(&pref[swz(bb[j])], 1);
    skey[p] = x[j];
  }
  __syncthreads();

  // position-ordered rank + fused dot. Position p's value y: recompute its
  // bin (pure function of y -> consistent with histogram), rank within the
  // segment with tie-break by position (p IS the scatter position; ties are
  // bitwise-equal values so the result is deterministic).
  const float* vrow = v + (size_t)l * Nc;
  float acc = 0.f;
  #pragma unroll
  for (int k = 0; k < EL; ++k) {
    int p = tid + NT * k;
    float y = skey[p];
    int b = (int)((y - LO) * SCALE);
    b = b < 0 ? 0 : (b > NB - 1 ? NB - 1 : b);
    int lo_ = b ? pref[swz(b - 1)] : 0;
    int hi_ = pref[swz(b)];
    int r = lo_;
    for (int q = lo_; q < hi_; ++q) {
      float z = skey[q];
      r += (z < y || (z == y && q < p)) ? 1 : 0;
    }
    acc += y * vrow[r];
  }

  #pragma unroll
  for (int off = 1; off < 64; off <<= 1) acc += __shfl_xor(acc, off, 64);
  __syncthreads();  // all pref reads done before red (aliased) is written
  if ((tid & 63) == 0) red[tid >> 6] = acc;
  __syncthreads();
  if (tid == 0) {
    float t = 0.f;
    #pragma unroll
    for (int ww = 0; ww < 8; ++ww) t += red[ww];
    int b = b0 + bloc;
    out[(size_t)b * Lc + l] = C[l] - t;
  }
}

// ---------------------------------------------------------------------------
extern "C" void kernel_launch(void* const* d_in, const int* in_sizes, int n_in,
                              void* d_out, int out_size, void* d_ws, size_t ws_size,
                              hipStream_t stream) {
  const float* X       = (const float*)d_in[0];  // [B,N,D]
  const float* theta_v = (const float*)d_in[1];  // [L,D]
  const float* ref     = (const float*)d_in[2];  // [M,L]
  const float* weight  = (const float*)d_in[3];  // [L,M]
  float* out = (float*)d_out;                    // [B,L]

  // workspace layout: v [L*N] f32 | Wh,Wl [L*D] u16 | C [128] f32 | sl
  float* v  = (float*)d_ws;
  unsigned short* Wh = (unsigned short*)(v + (size_t)Lc * Nc);
  unsigned short* Wl = Wh + (size_t)Lc * Dc;
  float* Cc = (float*)(Wl + (size_t)Lc * Dc);
  float* sl = Cc + 128;
  size_t used = (size_t)((char*)sl - (char*)d_ws);
  size_t per_b = (size_t)Lc * Nc * sizeof(float);  // 2 MB per batch element
  int chunk = 1;
  if (ws_size > used + per_b) {
    size_t c = (ws_size - used) / per_b;
    chunk = (int)(c > (size_t)Bc ? (size_t)Bc : c);
    if (chunk < 1) chunk = 1;
  }
  // cap chunk so the sl chunk (~2 MB/b) stays L2-resident between the
  // producing gemm and consuming rank_dot -> no HBM writeback contention
  if (chunk > 16) chunk = 16;

  prep_kernel<<<Lc, 128, 0, stream>>>(theta_v, ref, weight, Wh, Wl, Cc);
  build_v_kernel<<<Lc, 256, 0, stream>>>(ref, weight, v);

  for (int b0 = 0; b0 < Bc; b0 += chunk) {
    int nb = (Bc - b0) < chunk ? (Bc - b0) : chunk;
    dim3 g1(Nc / 128, nb);
    gemm_kernel<<<g1, 256, 0, stream>>>(X + (size_t)b0 * Nc * Dc, Wh, Wl, sl);
    rank_dot_kernel<<<(size_t)nb * Lc, 512, 0, stream>>>(sl, v, Cc, out, b0);
  }
}

// Round 7
// 173.992 us; speedup vs baseline: 3.5397x; 1.1899x over previous
//
#include <hip/hip_runtime.h>

// Problem constants
static constexpr int Bc = 64;     // batch
static constexpr int Nc = 4096;   // set size
static constexpr int Dc = 128;    // d_in
static constexpr int Mc = 1024;   // num ref points
static constexpr int Lc = 128;    // num projections

using short8   = __attribute__((ext_vector_type(8))) short;
using ushort8v = __attribute__((ext_vector_type(8))) unsigned short;
using f32x4    = __attribute__((ext_vector_type(4))) float;

__device__ __forceinline__ unsigned short f2bf(float x) {
  unsigned u = __builtin_bit_cast(unsigned, x);
  return (unsigned short)((u + 0x7FFFu + ((u >> 16) & 1u)) >> 16);
}
__device__ __forceinline__ float bf2f(unsigned short h) {
  unsigned u = ((unsigned)h) << 16;
  return __builtin_bit_cast(float, u);
}

__device__ __forceinline__ int swz(int i) { return i ^ ((i >> 4) & 31); }

// ---------------------------------------------------------------------------
// Kernel 1 (setup): per l-block (128 blocks x 256 threads):
//   - Wh/Wl[l][d] = bf16 hi/lo split of theta_v[l]/||theta_v[l]||
//   - C[l] = sum_m ref[m,l]*weight[l,m]
//   - v[l][n]: binning-rank argsort of ref column (stable, (val,idx) order)
//     + interp-stencil scatter of permuted weights
// ---------------------------------------------------------------------------
__global__ __launch_bounds__(256) void setup_kernel(
    const float* __restrict__ theta_v, const float* __restrict__ ref,
    const float* __restrict__ weight, unsigned short* __restrict__ Wh,
    unsigned short* __restrict__ Wl, float* __restrict__ C,
    float* __restrict__ v) {
  constexpr int NBv = 2048;
  constexpr float LOv = -4.2f;
  constexpr float SCv = (float)NBv / 8.4f;

  __shared__ int pref[NBv];            // 8 KB
  __shared__ float skey[Mc];           // 4 KB
  __shared__ unsigned short sidx[Mc];  // 2 KB
  __shared__ float vrow[Nc];           // 16 KB
  __shared__ int wsum[4];
  __shared__ float s2[2];
  __shared__ float c4[4];

  int l = blockIdx.x;
  int tid = threadIdx.x;
  int lane = tid & 63, wv = tid >> 6;

  // ref column (also reused for C)
  float x[4];
  #pragma unroll
  for (int j = 0; j < 4; ++j) x[j] = ref[(size_t)(tid + 256 * j) * Lc + l];

  for (int i = tid; i < NBv; i += 256) pref[i] = 0;
  for (int i = tid; i < Nc; i += 256) vrow[i] = 0.f;

  // W-norm partial (threads 0..127; waves 0,1)
  float wval = 0.f;
  if (tid < Dc) {
    wval = theta_v[l * Dc + tid];
    float sq = wval * wval;
    #pragma unroll
    for (int off = 1; off < 64; off <<= 1) sq += __shfl_xor(sq, off, 64);
    if (lane == 0) s2[wv] = sq;
  }
  // C partial (all threads, reuses x)
  {
    float cacc = 0.f;
    #pragma unroll
    for (int j = 0; j < 4; ++j) cacc += x[j] * weight[(size_t)l * Mc + tid + 256 * j];
    #pragma unroll
    for (int off = 1; off < 64; off <<= 1) cacc += __shfl_xor(cacc, off, 64);
    if (lane == 0) c4[wv] = cacc;
  }
  __syncthreads();

  if (tid < Dc) {
    float norm = sqrtf(s2[0] + s2[1]);
    float val = wval / norm;
    unsigned short hi = f2bf(val);
    Wh[l * Dc + tid] = hi;
    Wl[l * Dc + tid] = f2bf(val - bf2f(hi));
  }
  if (tid == 0) C[l] = c4[0] + c4[1] + c4[2] + c4[3];

  // histogram
  int bb[4];
  #pragma unroll
  for (int j = 0; j < 4; ++j) {
    int bi = (int)((x[j] - LOv) * SCv);
    bi = bi < 0 ? 0 : (bi > NBv - 1 ? NBv - 1 : bi);
    bb[j] = bi;
    atomicAdd(&pref[swz(bi)], 1);
  }
  __syncthreads();

  // exclusive prefix over 2048 bins (8/thread)
  {
    int base_ = tid * 8;
    int loc[8]; int s = 0;
    #pragma unroll
    for (int j = 0; j < 8; ++j) loc[j] = pref[swz(base_ + j)];
    #pragma unroll
    for (int j = 0; j < 8; ++j) { int c = loc[j]; loc[j] = s; s += c; }
    int inc = s;
    #pragma unroll
    for (int off = 1; off < 64; off <<= 1) {
      int o = __shfl_up(inc, off, 64);
      if (lane >= off) inc += o;
    }
    if (lane == 63) wsum[wv] = inc;
    __syncthreads();
    int wbase = 0;
    #pragma unroll
    for (int ww = 0; ww < 4; ++ww) if (ww < wv) wbase += wsum[ww];
    int tbase = wbase + inc - s;
    #pragma unroll
    for (int j = 0; j < 8; ++j) pref[swz(base_ + j)] = tbase + loc[j];
  }
  __syncthreads();

  // scatter (value, orig idx)
  #pragma unroll
  for (int j = 0; j < 4; ++j) {
    int p = atomicAdd(&pref[swz(bb[j])], 1);
    skey[p] = x[j];
    sidx[p] = (unsigned short)(tid + 256 * j);
  }
  __syncthreads();

  // position-ordered exact rank (stable: (value, orig idx)) + stencil scatter
  #pragma unroll
  for (int k = 0; k < 4; ++k) {
    int p = tid + 256 * k;
    float y = skey[p];
    int m = sidx[p];
    int b = (int)((y - LOv) * SCv);
    b = b < 0 ? 0 : (b > NBv - 1 ? NBv - 1 : b);
    int lo_ = b ? pref[swz(b - 1)] : 0;
    int hi_ = pref[swz(b)];
    int r = lo_;
    for (int q = lo_; q < hi_; ++q) {
      float z = skey[q];
      r += (z < y || (z == y && sidx[q] < m)) ? 1 : 0;
    }
    // element with original index m has rank r in the stable argsort
    float wvv = weight[(size_t)l * Mc + r];
    double pos = (double)(m + 1) * (double)(Nc + 1) / (double)(Mc + 1) - 1.0;
    int i0 = (int)pos;
    float t = (float)(pos - (double)i0);
    atomicAdd(&vrow[i0], (1.0f - t) * wvv);
    atomicAdd(&vrow[i0 + 1], t * wvv);
  }
  __syncthreads();
  for (int i = tid; i < Nc; i += 256) v[(size_t)l * Nc + i] = vrow[i];
}

// ---------------------------------------------------------------------------
// Kernel 2: MFMA GEMM, f32 = bf16 hi + lo (3-term).
//  - A (X) fragments loaded DIRECTLY from global (no LDS round-trip),
//    converted in-register; B (W) staged per-chunk in LDS (shared by waves).
// sl[bloc][l][n] = sum_d X[bloc,n,d] * W[l,d]
// ---------------------------------------------------------------------------
__global__ __launch_bounds__(256) void gemm_kernel(
    const float* __restrict__ X, const unsigned short* __restrict__ Whp,
    const unsigned short* __restrict__ Wlp, float* __restrict__ sl) {
  __shared__ unsigned short Bh[128][40];  // 10 KB
  __shared__ unsigned short Bl[128][40];  // 10 KB

  int bloc = blockIdx.y;
  int nbase = blockIdx.x * 128;
  int tid = threadIdx.x;
  int lane = tid & 63;
  int w = tid >> 6;
  int m16 = lane & 15;
  int kg = lane >> 4;

  const float* arow0 = X + ((size_t)bloc * Nc + nbase + w * 32 + m16) * Dc;
  const float* arow1 = arow0 + (size_t)16 * Dc;

  f32x4 acc[2][8] = {};

  for (int d0 = 0; d0 < Dc; d0 += 32) {
    __syncthreads();
    // stage B chunk: 128 rows x 32 d (hi & lo), 2 ushort8 per thread per array
    #pragma unroll
    for (int s = 0; s < 2; ++s) {
      int idx = tid * 2 + s;
      int row = idx >> 2;
      int c = (idx & 3) * 8;
      *(ushort8v*)&Bh[row][c] = *(const ushort8v*)(Whp + (size_t)row * Dc + d0 + c);
      *(ushort8v*)&Bl[row][c] = *(const ushort8v*)(Wlp + (size_t)row * Dc + d0 + c);
    }
    __syncthreads();

    // A fragments: direct global + in-register hi/lo convert
    short8 ah[2], al[2];
    #pragma unroll
    for (int t = 0; t < 2; ++t) {
      const float* ap = (t ? arow1 : arow0) + d0 + kg * 8;
      float4 f0 = *(const float4*)ap;
      float4 f1 = *(const float4*)(ap + 4);
      float xs[8] = {f0.x, f0.y, f0.z, f0.w, f1.x, f1.y, f1.z, f1.w};
      short8 hi, lo;
      #pragma unroll
      for (int e = 0; e < 8; ++e) {
        unsigned short h = f2bf(xs[e]);
        hi[e] = (short)h;
        lo[e] = (short)f2bf(xs[e] - bf2f(h));
      }
      ah[t] = hi; al[t] = lo;
    }

    #pragma unroll
    for (int u = 0; u < 8; ++u) {
      short8 bh = *(const short8*)&Bh[u * 16 + m16][kg * 8];
      short8 bl = *(const short8*)&Bl[u * 16 + m16][kg * 8];
      #pragma unroll
      for (int t = 0; t < 2; ++t) {
        acc[t][u] = __builtin_amdgcn_mfma_f32_16x16x32_bf16(ah[t], bh, acc[t][u], 0, 0, 0);
        acc[t][u] = __builtin_amdgcn_mfma_f32_16x16x32_bf16(ah[t], bl, acc[t][u], 0, 0, 0);
        acc[t][u] = __builtin_amdgcn_mfma_f32_16x16x32_bf16(al[t], bh, acc[t][u], 0, 0, 0);
      }
    }
  }

  #pragma unroll
  for (int t = 0; t < 2; ++t) {
    #pragma unroll
    for (int u = 0; u < 8; ++u) {
      int l = u * 16 + m16;
      int n0 = nbase + w * 32 + t * 16 + kg * 4;
      float* dst = sl + ((size_t)bloc * Lc + l) * Nc + n0;
      *(float4*)dst = *(float4*)&acc[t][u];
    }
  }
}

// ---------------------------------------------------------------------------
// Kernel 3: radix-rank + fused dot, 512 threads (8 waves/block).
// ---------------------------------------------------------------------------
__global__ __launch_bounds__(512, 8) void rank_dot_kernel(
    const float* __restrict__ sl, const float* __restrict__ v,
    const float* __restrict__ C, float* __restrict__ out, int b0) {
  constexpr int NB = 4096;
  constexpr float LO = -4.2f;
  constexpr float SCALE = (float)NB / 8.4f;
  constexpr int NT = 512;
  constexpr int EL = Nc / NT;  // 8 elements per thread

  __shared__ int pref[NB];       // hist -> excl prefix -> incl prefix; then red
  __shared__ float skey[Nc];     // (wsum during scan) bin-ordered keys
  int* wsum = (int*)skey;        // live only during scan (before skey writes)
  float* red = (float*)pref;     // live only after final barrier

  int l = blockIdx.x & (Lc - 1);
  int bloc = blockIdx.x >> 7;
  int tid = threadIdx.x;
  const float* src = sl + ((size_t)bloc * Lc + l) * Nc;

  // coalesced strided load: thread owns float4s {tid + 512*j}
  float x[EL];
  {
    const float4* s4 = (const float4*)src;
    #pragma unroll
    for (int j = 0; j < EL / 4; ++j) {
      float4 f = s4[tid + NT * j];
      x[j * 4 + 0] = f.x; x[j * 4 + 1] = f.y;
      x[j * 4 + 2] = f.z; x[j * 4 + 3] = f.w;
    }
  }

  for (int i = tid; i < NB; i += NT) pref[i] = 0;
  __syncthreads();

  // histogram (swizzled layout)
  int bb[EL];
  #pragma unroll
  for (int j = 0; j < EL; ++j) {
    int bi = (int)((x[j] - LO) * SCALE);
    bi = bi < 0 ? 0 : (bi > NB - 1 ? NB - 1 : bi);
    bb[j] = bi;
    atomicAdd(&pref[swz(bi)], 1);
  }
  __syncthreads();

  // exclusive prefix sum over 4096 logical bins (8 bins/thread)
  {
    int base_ = tid * 8;
    int loc[8]; int s = 0;
    #pragma unroll
    for (int j = 0; j < 8; ++j) loc[j] = pref[swz(base_ + j)];
    #pragma unroll
    for (int j = 0; j < 8; ++j) { int c = loc[j]; loc[j] = s; s += c; }
    int lane = tid & 63, wv = tid >> 6;
    int inc = s;
    #pragma unroll
    for (int off = 1; off < 64; off <<= 1) {
      int o = __shfl_up(inc, off, 64);
      if (lane >= off) inc += o;
    }
    if (lane == 63) wsum[wv] = inc;
    __syncthreads();
    int wbase = 0;
    #pragma unroll
    for (int ww = 0; ww < 8; ++ww) if (ww < wv) wbase += wsum[ww];
    int tbase = wbase + inc - s;  // exclusive across threads
    #pragma unroll
    for (int j = 0; j < 8; ++j) pref[swz(base_ + j)] = tbase + loc[j];
  }
  __syncthreads();

  // scatter into bin-ordered array; pref[b] becomes inclusive end of bin b
  #pragma unroll
  for (int j = 0; j < EL; ++j) {
    int p = atomicAdd(&pref[swz(bb[j])], 1);
    skey[p] = x[j];
  }
  __syncthreads();

  // position-ordered rank + fused dot (tie-break by scatter position; ties
  // are bitwise-equal values so the result is deterministic).
  const float* vrow = v + (size_t)l * Nc;
  float acc = 0.f;
  #pragma unroll
  for (int k = 0; k < EL; ++k) {
    int p = tid + NT * k;
    float y = skey[p];
    int b = (int)((y - LO) * SCALE);
    b = b < 0 ? 0 : (b > NB - 1 ? NB - 1 : b);
    int lo_ = b ? pref[swz(b - 1)] : 0;
    int hi_ = pref[swz(b)];
    int r = lo_;
    for (int q = lo_; q < hi_; ++q) {
      float z = skey[q];
      r += (z < y || (z == y && q < p)) ? 1 : 0;
    }
    acc += y * vrow[r];
  }

  #pragma unroll
  for (int off = 1; off < 64; off <<= 1) acc += __shfl_xor(acc, off, 64);
  __syncthreads();  // all pref reads done before red (aliased) is written
  if ((tid & 63) == 0) red[tid >> 6] = acc;
  __syncthreads();
  if (tid == 0) {
    float t = 0.f;
    #pragma unroll
    for (int ww = 0; ww < 8; ++ww) t += red[ww];
    int b = b0 + bloc;
    out[(size_t)b * Lc + l] = C[l] - t;
  }
}

// ---------------------------------------------------------------------------
extern "C" void kernel_launch(void* const* d_in, const int* in_sizes, int n_in,
                              void* d_out, int out_size, void* d_ws, size_t ws_size,
                              hipStream_t stream) {
  const float* X       = (const float*)d_in[0];  // [B,N,D]
  const float* theta_v = (const float*)d_in[1];  // [L,D]
  const float* ref     = (const float*)d_in[2];  // [M,L]
  const float* weight  = (const float*)d_in[3];  // [L,M]
  float* out = (float*)d_out;                    // [B,L]

  // workspace layout: v [L*N] f32 | Wh,Wl [L*D] u16 | C [128] f32 | sl
  float* v  = (float*)d_ws;
  unsigned short* Wh = (unsigned short*)(v + (size_t)Lc * Nc);
  unsigned short* Wl = Wh + (size_t)Lc * Dc;
  float* Cc = (float*)(Wl + (size_t)Lc * Dc);
  float* sl = Cc + 128;
  size_t used = (size_t)((char*)sl - (char*)d_ws);
  size_t per_b = (size_t)Lc * Nc * sizeof(float);  // 2 MB per batch element
  int chunk = 1;
  if (ws_size > used + per_b) {
    size_t c = (ws_size - used) / per_b;
    chunk = (int)(c > (size_t)Bc ? (size_t)Bc : c);
    if (chunk < 1) chunk = 1;
  }

  setup_kernel<<<Lc, 256, 0, stream>>>(theta_v, ref, weight, Wh, Wl, Cc, v);

  for (int b0 = 0; b0 < Bc; b0 += chunk) {
    int nb = (Bc - b0) < chunk ? (Bc - b0) : chunk;
    dim3 g1(Nc / 128, nb);
    gemm_kernel<<<g1, 256, 0, stream>>>(X + (size_t)b0 * Nc * Dc, Wh, Wl, sl);
    rank_dot_kernel<<<(size_t)nb * Lc, 512, 0, stream>>>(sl, v, Cc, out, b0);
  }
}